// Round 1
// baseline (492.992 us; speedup 1.0000x reference)
//
#include <hip/hip_runtime.h>
#include <hip/hip_bf16.h>
#include <math.h>

#define NN 2048
#define CHAIN 512
#define KNN 30
#define LRK 10
#define NFIX 40
#define MAXE 42

#define OUT_ROT 0
#define OUT_TRANS (NN*9)
#define OUT_BB (NN*9 + NN*3)

// Set to 0 to use the pre-partitionable ("original") threefry counter layout.
#define THREEFRY_PARTITIONABLE 1

// ---------------- threefry2x32, key = (0, 42) ----------------
__device__ __forceinline__ unsigned rotl32(unsigned x, unsigned r){ return (x<<r)|(x>>(32u-r)); }

__device__ __forceinline__ void tf_block(unsigned &x0, unsigned &x1){
  const unsigned k0 = 0u, k1 = 42u, k2 = 0x1BD11BDAu ^ 0u ^ 42u;
  x0 += k0; x1 += k1;
#define TFR(a) x0 += x1; x1 = rotl32(x1,(a)); x1 ^= x0;
  TFR(13) TFR(15) TFR(26) TFR(6)   x0 += k1; x1 += k2 + 1u;
  TFR(17) TFR(29) TFR(16) TFR(24)  x0 += k2; x1 += k0 + 2u;
  TFR(13) TFR(15) TFR(26) TFR(6)   x0 += k0; x1 += k1 + 3u;
  TFR(17) TFR(29) TFR(16) TFR(24)  x0 += k1; x1 += k2 + 4u;
  TFR(13) TFR(15) TFR(26) TFR(6)   x0 += k2; x1 += k0 + 5u;
#undef TFR
}

__device__ __forceinline__ float gumbel_from_bits(unsigned bits){
  float f = __uint_as_float((bits >> 9) | 0x3f800000u) - 1.0f;
  const float tiny = 1.17549435e-38f;
  float u = fmaxf(tiny, f * (1.0f - tiny) + tiny);
  return -logf(-logf(u));
}

__device__ __forceinline__ float gumbel_at(unsigned p){
#if THREEFRY_PARTITIONABLE
  unsigned x0 = 0u, x1 = p;   // 64-bit linear counter, hi word = 0
  tf_block(x0, x1);
  return gumbel_from_bits(x0 ^ x1);
#else
  const unsigned HALF = (NN*(unsigned)NN)/2u;
  unsigned c0, c1; bool lo = p < HALF;
  if(lo){ c0 = p; c1 = p + HALF; } else { c0 = p - HALF; c1 = p; }
  tf_block(c0, c1);
  return gumbel_from_bits(lo ? c0 : c1);
#endif
}

// ---------------- K1: per-node prep: fused rows, P = fused@Wv, U/V = x0@Wa1 halves ----
__global__ __launch_bounds__(256) void k_prep(
    const float* __restrict__ rots, const float* __restrict__ trans,
    const float* __restrict__ nf, const float* __restrict__ Wa1,
    const float* __restrict__ Wv, const int* __restrict__ xmask,
    const int* __restrict__ nmask,
    float* __restrict__ P, float* __restrict__ U, float* __restrict__ V)
{
  __shared__ float fr[4][132];
  int n = blockIdx.x, t = threadIdx.x;
  if(t < 128){
    fr[0][t] = nf[n*512 + t];
    fr[1][t] = nf[n*512 + 128 + t];
    fr[2][t] = nf[n*512 + 256 + t];
    fr[3][t] = nf[n*512 + 384 + t];
  } else if(t == 128){
    fr[0][128] = 0.0f; fr[0][129] = 0.0f;
    fr[0][130] = (nmask[n] != 0 && xmask[n] == 0) ? 1.0f : 0.0f;
  } else if(t >= 160 && t < 169){
    int q = t - 160; int a = q / 3, i = q % 3;
    const float BB[3][3] = {{-0.525f,1.363f,0.0f},{0.f,0.f,0.f},{1.526f,0.f,0.f}};
    float bb = rots[n*9+i*3+0]*BB[a][0] + rots[n*9+i*3+1]*BB[a][1]
             + rots[n*9+i*3+2]*BB[a][2] + trans[n*3+i];
    fr[1+i][128+a] = bb;   // fused[n, 1+coord, 128+atom]
  }
  __syncthreads();
  // P[n][c][u], u = t
  float a0=0.f,a1=0.f,a2=0.f,a3=0.f;
  for(int j=0;j<131;j++){
    float w = Wv[j*256 + t];
    a0 += fr[0][j]*w; a1 += fr[1][j]*w; a2 += fr[2][j]*w; a3 += fr[3][j]*w;
  }
  P[n*1024       + t] = a0;
  P[n*1024 + 256 + t] = a1;
  P[n*1024 + 512 + t] = a2;
  P[n*1024 + 768 + t] = a3;
  if(t < 128){
    float s = 0.f;
    for(int j=0;j<131;j++) s += fr[0][j]*Wa1[j*128 + t];
    U[n*128 + t] = s;
  } else {
    int k = t - 128; float s = 0.f;
    for(int j=0;j<131;j++) s += fr[0][j]*Wa1[(131+j)*128 + k];
    V[n*128 + k] = s;
  }
}

// ---------------- K2: per-row d2 + gumbel score, top-30 (knn) + top-10 (lr) ---------
__global__ __launch_bounds__(64) void k_topk(
    const float* __restrict__ trans, int* __restrict__ srcs)
{
  __shared__ float d2s[NN];
  __shared__ float scs[NN];
  int i = blockIdx.x; int lane = threadIdx.x;
  float tx = trans[i*3+0], ty = trans[i*3+1], tz = trans[i*3+2];
  int ci = i >> 9;
  for(int j=lane;j<NN;j+=64){
    float dx = __fsub_rn(trans[j*3+0], tx);
    float dy = __fsub_rn(trans[j*3+1], ty);
    float dz = __fsub_rn(trans[j*3+2], tz);
    float d2 = __fadd_rn(__fadd_rn(__fmul_rn(dx,dx),__fmul_rn(dy,dy)),__fmul_rn(dz,dz));
    bool val = ((j>>9) == ci) && (j != i);
    float dm = val ? d2 : 1e30f;
    d2s[j] = dm;
    float g = gumbel_at((unsigned)(i*NN + j));
    scs[j] = __fadd_rn(__fmul_rn(-1.5f, logf(dm)), g);
  }
  __syncthreads();
  // ---- KNN: 30 smallest d2, tie -> lower index ----
  unsigned long long best = ~0ull;
  for(int j=lane;j<NN;j+=64){
    unsigned long long kk = ((unsigned long long)__float_as_uint(d2s[j])<<32) | (unsigned)j;
    if(kk < best) best = kk;
  }
  for(int k=0;k<KNN;k++){
    unsigned long long r = best;
    for(int off=32; off; off>>=1){
      unsigned long long o = __shfl_xor(r, off, 64);
      if(o < r) r = o;
    }
    int win = (int)(unsigned)(r & 0xffffffffull);
    if(lane == 0){ srcs[i*NFIX + k] = win; d2s[win] = __uint_as_float(0x7f800000u); }
    __syncthreads();
    if((win & 63) == lane){
      best = ~0ull;
      for(int j=lane;j<NN;j+=64){
        unsigned long long kk = ((unsigned long long)__float_as_uint(d2s[j])<<32) | (unsigned)j;
        if(kk < best) best = kk;
      }
    }
  }
  // ---- LR: 10 largest score, tie -> lower index ----
  unsigned long long bmax = 0ull;
  for(int j=lane;j<NN;j+=64){
    unsigned b = __float_as_uint(scs[j]);
    unsigned ord = b ^ ((b & 0x80000000u) ? 0xFFFFFFFFu : 0x80000000u);
    unsigned long long kk = ((unsigned long long)ord<<32) | (unsigned)(NN-1-j);
    if(kk > bmax) bmax = kk;
  }
  for(int k=0;k<LRK;k++){
    unsigned long long r = bmax;
    for(int off=32; off; off>>=1){
      unsigned long long o = __shfl_xor(r, off, 64);
      if(o > r) r = o;
    }
    int win = NN-1 - (int)(unsigned)(r & 0xffffffffull);
    if(lane == 0){ srcs[i*NFIX + KNN + k] = win; scs[win] = __uint_as_float(0xFF800000u); }
    __syncthreads();
    if((win & 63) == lane){
      bmax = 0ull;
      for(int j=lane;j<NN;j+=64){
        unsigned b = __float_as_uint(scs[j]);
        unsigned ord = b ^ ((b & 0x80000000u) ? 0xFFFFFFFFu : 0x80000000u);
        unsigned long long kk = ((unsigned long long)ord<<32) | (unsigned)(NN-1-j);
        if(kk > bmax) bmax = kk;
      }
    }
  }
}

// ---------------- K3: per-dst fused attention + aggregation + node MLPs ------------
__global__ __launch_bounds__(256) void k_main(
    const float* __restrict__ rots, const float* __restrict__ trans,
    const float* __restrict__ Wa1, const float* __restrict__ ba1,
    const float* __restrict__ Wa2, const float* __restrict__ Wo,
    const float* __restrict__ Wg, const float* __restrict__ Wf1,
    const float* __restrict__ Wf2, const float* __restrict__ Wr1,
    const float* __restrict__ br1, const float* __restrict__ Wr2,
    const float* __restrict__ br2, const float* __restrict__ Wr3,
    const float* __restrict__ br3, const float* __restrict__ Wt,
    const int* __restrict__ nmask,
    const float* __restrict__ P, const float* __restrict__ U, const float* __restrict__ V,
    const int* __restrict__ srcs, float* __restrict__ out)
{
  __shared__ int   s_src[MAXE];
  __shared__ int   s_val[MAXE];
  __shared__ float s_att[MAXE*8];
  __shared__ float s_ef[4][32];
  __shared__ float s_agg[4][256];
  __shared__ float s_out[4][128];
  __shared__ float s_gate[128];
  __shared__ float s_t1[128];
  __shared__ float s_bb0[128];
  __shared__ float s_h1[256];
  __shared__ float s_h2[128];
  __shared__ float s_qv[3];
  __shared__ float s_tu[3];

  int d = blockIdx.x, t = threadIdx.x;
  int wave = t >> 6, lane = t & 63;
  int pos = d & (CHAIN-1);
  int nE = NFIX + (pos != 0 ? 1 : 0) + (pos != CHAIN-1 ? 1 : 0);
  if(t < NFIX) s_src[t] = srcs[d*NFIX + t];
  if(t == NFIX) s_src[NFIX] = (pos != 0) ? d-1 : d+1;            // first seq neighbor
  if(t == NFIX+1 && pos != 0 && pos != CHAIN-1) s_src[NFIX+1] = d+1;
  __syncthreads();

  float tdx = trans[d*3+0], tdy = trans[d*3+1], tdz = trans[d*3+2];
  float vb0 = V[d*128 + lane], vb1 = V[d*128 + 64 + lane];
  float bbias0 = ba1[lane], bbias1 = ba1[64 + lane];

  for(int e = wave; e < nE; e += 4){
    int src = s_src[e];
    float dx = trans[src*3+0]-tdx, dy = trans[src*3+1]-tdy, dz = trans[src*3+2]-tdz;
    float dist = sqrtf(dx*dx + dy*dy + dz*dz + 1e-12f);
    int valid = (dist > 1e-3f) ? 1 : 0;
    float rel = (float)(src - d);
    if(lane < 16){
      float mu = (float)lane * (20.0f/15.0f);
      float zz = (dist - mu) / 1.25f;
      s_ef[wave][lane] = expf(-(zz*zz));
    } else if(lane < 32){
      int idx = lane - 16; int j = idx & 7;
      float fr = expf((float)(2*j) * (float)(-0.5756462732485115));
      float ang = rel * fr;
      s_ef[wave][lane] = (idx < 8) ? cosf(ang) : sinf(ang);
    }
    asm volatile("s_waitcnt lgkmcnt(0)" ::: "memory");
    __builtin_amdgcn_wave_barrier();
    float h0 = bbias0 + U[src*128 + lane]      + vb0;
    float h1 = bbias1 + U[src*128 + 64 + lane] + vb1;
    for(int f=0; f<32; f++){
      float ev = s_ef[wave][f];
      h0 += ev * Wa1[(262+f)*128 + lane];
      h1 += ev * Wa1[(262+f)*128 + 64 + lane];
    }
    h0 = (h0 >= 0.0f) ? h0 : 0.01f*h0;
    h1 = (h1 >= 0.0f) ? h1 : 0.01f*h1;
    for(int h=0; h<8; h++){
      float part = h0 * Wa2[lane*8 + h] + h1 * Wa2[(64+lane)*8 + h];
      for(int off=32; off; off>>=1) part += __shfl_xor(part, off, 64);
      if(lane == 0) s_att[e*8 + h] = valid ? part : -1e30f;
    }
    if(lane == 1) s_val[e] = valid;
  }
  __syncthreads();

  if(t < 8){   // per-head softmax over this dst's edges
    float m = -INFINITY;
    for(int e=0;e<nE;e++) m = fmaxf(m, s_att[e*8+t]);
    m = (m > -5e29f) ? m : 0.0f;
    float z = 0.0f;
    for(int e=0;e<nE;e++){
      float p = s_val[e] ? expf(s_att[e*8+t] - m) : 0.0f;
      s_att[e*8+t] = p; z += p;
    }
    float den = z + 1e-9f;
    for(int e=0;e<nE;e++) s_att[e*8+t] = s_att[e*8+t] / den;
  }
  __syncthreads();

  {  // agg[c][u] = sum_e attn[e][u>>5] * P[src][c][u]   (rotations cancel exactly)
    float a0=0.f,a1=0.f,a2=0.f,a3=0.f; int h = t >> 5;
    for(int e=0;e<nE;e++){
      float w = s_att[e*8 + h];
      const float* Pr = P + s_src[e]*1024 + t;
      a0 += w*Pr[0]; a1 += w*Pr[256]; a2 += w*Pr[512]; a3 += w*Pr[768];
    }
    s_agg[0][t]=a0; s_agg[1][t]=a1; s_agg[2][t]=a2; s_agg[3][t]=a3;
  }
  __syncthreads();

  {  // out = agg @ Wo : 512 outputs, 2 per thread
    int o1 = t, o2 = t + 256;
    int c1 = o1 >> 7, k1 = o1 & 127, c2 = o2 >> 7, k2 = o2 & 127;
    float x1=0.f, x2=0.f;
    for(int u=0;u<256;u++){
      x1 += s_agg[c1][u] * Wo[u*128 + k1];
      x2 += s_agg[c2][u] * Wo[u*128 + k2];
    }
    s_out[c1][k1] = x1; s_out[c2][k2] = x2;
  }
  __syncthreads();

  if(t < 128){
    float g=0.f, f1=0.f;
    for(int k=0;k<128;k++){
      float yv = s_out[0][k];
      g  += yv * Wg[k*128 + t];
      f1 += yv * Wf1[k*128 + t];
    }
    s_gate[t] = 1.0f/(1.0f + expf(-g));
    s_t1[t] = fmaxf(f1, 0.0f);
  }
  __syncthreads();
  if(t < 128){
    float f0=0.f;
    for(int k=0;k<128;k++) f0 += s_t1[k] * Wf2[k*128 + t];
    float b0 = s_out[0][t] + f0;
    s_bb0[t] = b0;
    out[OUT_BB + d*512 + t] = b0;
    float gt = s_gate[t];
    for(int c=1;c<4;c++){
      float v = s_out[c][t] * gt;
      s_out[c][t] = v;                       // gated, reused for trans_update
      out[OUT_BB + d*512 + c*128 + t] = v;
    }
  }
  __syncthreads();
  {
    float a = br1[t];
    for(int k=0;k<128;k++) a += s_bb0[k] * Wr1[k*256 + t];
    s_h1[t] = fmaxf(a, 0.0f);
  }
  __syncthreads();
  if(t < 128){
    float a = br2[t];
    for(int k=0;k<256;k++) a += s_h1[k] * Wr2[k*128 + t];
    s_h2[t] = fmaxf(a, 0.0f);
  }
  __syncthreads();
  if(t < 3){
    float a = br3[t];
    for(int k=0;k<128;k++) a += s_h2[k] * Wr3[k*6 + t];
    s_qv[t] = a;
  } else if(t >= 4 && t < 7){
    int i = t - 4; float a = 0.f;
    for(int k=0;k<128;k++) a += s_out[1+i][k] * Wt[k];
    s_tu[i] = a;
  }
  __syncthreads();
  if(t == 0){
    int nz = nmask[d];
    float q1=s_qv[0], q2=s_qv[1], q3=s_qv[2];
    float nrm = sqrtf(1.0f + q1*q1 + q2*q2 + q3*q3);
    float w=1.0f/nrm, x=q1/nrm, y=q2/nrm, z=q3/nrm;
    float Ru[3][3];
    Ru[0][0]=1.f-2.f*(y*y+z*z); Ru[0][1]=2.f*(x*y-w*z);     Ru[0][2]=2.f*(x*z+w*y);
    Ru[1][0]=2.f*(x*y+w*z);     Ru[1][1]=1.f-2.f*(x*x+z*z); Ru[1][2]=2.f*(y*z-w*x);
    Ru[2][0]=2.f*(x*z-w*y);     Ru[2][1]=2.f*(y*z+w*x);     Ru[2][2]=1.f-2.f*(x*x+y*y);
    for(int i=0;i<3;i++){
      for(int j=0;j<3;j++){
        float rv;
        if(nz){
          rv = rots[d*9+i*3+0]*Ru[0][j] + rots[d*9+i*3+1]*Ru[1][j] + rots[d*9+i*3+2]*Ru[2][j];
        } else {
          rv = rots[d*9+i*3+j];
        }
        out[OUT_ROT + d*9 + i*3 + j] = rv;
      }
      float tv = trans[d*3+i];
      out[OUT_TRANS + d*3 + i] = nz ? (tv + s_tu[i]) : tv;
    }
  }
}

extern "C" void kernel_launch(void* const* d_in, const int* in_sizes, int n_in,
                              void* d_out, int out_size, void* d_ws, size_t ws_size,
                              hipStream_t stream)
{
  (void)in_sizes; (void)n_in; (void)out_size; (void)ws_size;
  const float* rots = (const float*)d_in[0];
  const float* trans = (const float*)d_in[1];
  const float* nf   = (const float*)d_in[2];
  const float* Wa1  = (const float*)d_in[3];
  const float* ba1  = (const float*)d_in[4];
  const float* Wa2  = (const float*)d_in[5];
  const float* Wv   = (const float*)d_in[6];
  const float* Wo   = (const float*)d_in[7];
  const float* Wg   = (const float*)d_in[8];
  const float* Wf1  = (const float*)d_in[9];
  const float* Wf2  = (const float*)d_in[10];
  const float* Wr1  = (const float*)d_in[11];
  const float* br1  = (const float*)d_in[12];
  const float* Wr2  = (const float*)d_in[13];
  const float* br2  = (const float*)d_in[14];
  const float* Wr3  = (const float*)d_in[15];
  const float* br3  = (const float*)d_in[16];
  const float* Wt   = (const float*)d_in[17];
  const int* xmask  = (const int*)d_in[19];
  const int* nmask  = (const int*)d_in[20];

  float* P = (float*)d_ws;                 // N*1024 f32
  float* U = P + NN*1024;                  // N*128
  float* V = U + NN*128;                   // N*128
  int* srcs = (int*)(V + NN*128);          // N*40 int

  k_prep<<<NN, 256, 0, stream>>>(rots, trans, nf, Wa1, Wv, xmask, nmask, P, U, V);
  k_topk<<<NN, 64, 0, stream>>>(trans, srcs);
  k_main<<<NN, 256, 0, stream>>>(rots, trans, Wa1, ba1, Wa2, Wo, Wg, Wf1, Wf2,
                                 Wr1, br1, Wr2, br2, Wr3, br3, Wt, nmask,
                                 P, U, V, srcs, (float*)d_out);
}

// Round 2
// 439.287 us; speedup vs baseline: 1.1223x; 1.1223x over previous
//
#include <hip/hip_runtime.h>
#include <hip/hip_bf16.h>
#include <math.h>

#define NN 2048
#define CHAIN 512
#define KNN 30
#define LRK 10
#define NFIX 40
#define NSLOT 42

#define OUT_ROT 0
#define OUT_TRANS (NN*9)
#define OUT_BB (NN*9 + NN*3)

#define THREEFRY_PARTITIONABLE 1

// XCD-aware swizzle: blocks b -> d so each XCD gets a contiguous 256-node slice
__device__ __forceinline__ int xcd_swz(int b){ return ((b & 7) << 8) | (b >> 3); }

// ---------------- threefry2x32, key = (0, 42) ----------------
__device__ __forceinline__ unsigned rotl32(unsigned x, unsigned r){ return (x<<r)|(x>>(32u-r)); }

__device__ __forceinline__ void tf_block(unsigned &x0, unsigned &x1){
  const unsigned k0 = 0u, k1 = 42u, k2 = 0x1BD11BDAu ^ 0u ^ 42u;
  x0 += k0; x1 += k1;
#define TFR(a) x0 += x1; x1 = rotl32(x1,(a)); x1 ^= x0;
  TFR(13) TFR(15) TFR(26) TFR(6)   x0 += k1; x1 += k2 + 1u;
  TFR(17) TFR(29) TFR(16) TFR(24)  x0 += k2; x1 += k0 + 2u;
  TFR(13) TFR(15) TFR(26) TFR(6)   x0 += k0; x1 += k1 + 3u;
  TFR(17) TFR(29) TFR(16) TFR(24)  x0 += k1; x1 += k2 + 4u;
  TFR(13) TFR(15) TFR(26) TFR(6)   x0 += k2; x1 += k0 + 5u;
#undef TFR
}

__device__ __forceinline__ float gumbel_from_bits(unsigned bits){
  float f = __uint_as_float((bits >> 9) | 0x3f800000u) - 1.0f;
  const float tiny = 1.17549435e-38f;
  float u = fmaxf(tiny, f * (1.0f - tiny) + tiny);
  return -logf(-logf(u));
}

__device__ __forceinline__ float gumbel_at(unsigned p){
#if THREEFRY_PARTITIONABLE
  unsigned x0 = 0u, x1 = p;
  tf_block(x0, x1);
  return gumbel_from_bits(x0 ^ x1);
#else
  const unsigned HALF = (NN*(unsigned)NN)/2u;
  unsigned c0, c1; bool lo = p < HALF;
  if(lo){ c0 = p; c1 = p + HALF; } else { c0 = p - HALF; c1 = p; }
  tf_block(c0, c1);
  return gumbel_from_bits(lo ? c0 : c1);
#endif
}

// ---------------- K1: per-node prep ----------------
__global__ __launch_bounds__(256) void k_prep(
    const float* __restrict__ rots, const float* __restrict__ trans,
    const float* __restrict__ nf, const float* __restrict__ Wa1,
    const float* __restrict__ Wv, const int* __restrict__ xmask,
    const int* __restrict__ nmask,
    float* __restrict__ P, float* __restrict__ U, float* __restrict__ V)
{
  __shared__ float fr[4][132];
  int n = blockIdx.x, t = threadIdx.x;
  if(t < 128){
    fr[0][t] = nf[n*512 + t];
    fr[1][t] = nf[n*512 + 128 + t];
    fr[2][t] = nf[n*512 + 256 + t];
    fr[3][t] = nf[n*512 + 384 + t];
  } else if(t == 128){
    fr[0][128] = 0.0f; fr[0][129] = 0.0f;
    fr[0][130] = (nmask[n] != 0 && xmask[n] == 0) ? 1.0f : 0.0f;
  } else if(t >= 160 && t < 169){
    int q = t - 160; int a = q / 3, i = q % 3;
    const float BB[3][3] = {{-0.525f,1.363f,0.0f},{0.f,0.f,0.f},{1.526f,0.f,0.f}};
    float bb = rots[n*9+i*3+0]*BB[a][0] + rots[n*9+i*3+1]*BB[a][1]
             + rots[n*9+i*3+2]*BB[a][2] + trans[n*3+i];
    fr[1+i][128+a] = bb;
  }
  __syncthreads();
  float a0=0.f,a1=0.f,a2=0.f,a3=0.f;
  for(int j=0;j<131;j++){
    float w = Wv[j*256 + t];
    a0 += fr[0][j]*w; a1 += fr[1][j]*w; a2 += fr[2][j]*w; a3 += fr[3][j]*w;
  }
  P[n*1024       + t] = a0;
  P[n*1024 + 256 + t] = a1;
  P[n*1024 + 512 + t] = a2;
  P[n*1024 + 768 + t] = a3;
  if(t < 128){
    float s = 0.f;
    for(int j=0;j<131;j++) s += fr[0][j]*Wa1[j*128 + t];
    U[n*128 + t] = s;
  } else {
    int k = t - 128; float s = 0.f;
    for(int j=0;j<131;j++) s += fr[0][j]*Wa1[(131+j)*128 + k];
    V[n*128 + k] = s;
  }
}

// ---------------- K2: per-row top-30 (knn) + top-10 (lr) ---------
__global__ __launch_bounds__(64) void k_topk(
    const float* __restrict__ trans, int* __restrict__ srcs)
{
  __shared__ float d2s[NN];
  __shared__ float scs[NN];
  int i = blockIdx.x; int lane = threadIdx.x;
  float tx = trans[i*3+0], ty = trans[i*3+1], tz = trans[i*3+2];
  int ci = i >> 9;
  for(int j=lane;j<NN;j+=64){
    float dx = __fsub_rn(trans[j*3+0], tx);
    float dy = __fsub_rn(trans[j*3+1], ty);
    float dz = __fsub_rn(trans[j*3+2], tz);
    float d2 = __fadd_rn(__fadd_rn(__fmul_rn(dx,dx),__fmul_rn(dy,dy)),__fmul_rn(dz,dz));
    bool val = ((j>>9) == ci) && (j != i);
    float dm = val ? d2 : 1e30f;
    d2s[j] = dm;
    float g = gumbel_at((unsigned)(i*NN + j));
    scs[j] = __fadd_rn(__fmul_rn(-1.5f, logf(dm)), g);
  }
  __syncthreads();
  unsigned long long best = ~0ull;
  for(int j=lane;j<NN;j+=64){
    unsigned long long kk = ((unsigned long long)__float_as_uint(d2s[j])<<32) | (unsigned)j;
    if(kk < best) best = kk;
  }
  for(int k=0;k<KNN;k++){
    unsigned long long r = best;
    for(int off=32; off; off>>=1){
      unsigned long long o = __shfl_xor(r, off, 64);
      if(o < r) r = o;
    }
    int win = (int)(unsigned)(r & 0xffffffffull);
    if(lane == 0){ srcs[i*NFIX + k] = win; d2s[win] = __uint_as_float(0x7f800000u); }
    __syncthreads();
    if((win & 63) == lane){
      best = ~0ull;
      for(int j=lane;j<NN;j+=64){
        unsigned long long kk = ((unsigned long long)__float_as_uint(d2s[j])<<32) | (unsigned)j;
        if(kk < best) best = kk;
      }
    }
  }
  unsigned long long bmax = 0ull;
  for(int j=lane;j<NN;j+=64){
    unsigned b = __float_as_uint(scs[j]);
    unsigned ord = b ^ ((b & 0x80000000u) ? 0xFFFFFFFFu : 0x80000000u);
    unsigned long long kk = ((unsigned long long)ord<<32) | (unsigned)(NN-1-j);
    if(kk > bmax) bmax = kk;
  }
  for(int k=0;k<LRK;k++){
    unsigned long long r = bmax;
    for(int off=32; off; off>>=1){
      unsigned long long o = __shfl_xor(r, off, 64);
      if(o > r) r = o;
    }
    int win = NN-1 - (int)(unsigned)(r & 0xffffffffull);
    if(lane == 0){ srcs[i*NFIX + KNN + k] = win; scs[win] = __uint_as_float(0xFF800000u); }
    __syncthreads();
    if((win & 63) == lane){
      bmax = 0ull;
      for(int j=lane;j<NN;j+=64){
        unsigned b = __float_as_uint(scs[j]);
        unsigned ord = b ^ ((b & 0x80000000u) ? 0xFFFFFFFFu : 0x80000000u);
        unsigned long long kk = ((unsigned long long)ord<<32) | (unsigned)(NN-1-j);
        if(kk > bmax) bmax = kk;
      }
    }
  }
}

// ---------------- K3: edge logits (one wave per edge slot) ------------
__global__ __launch_bounds__(256) void k_edge(
    const float* __restrict__ trans, const float* __restrict__ Wa1,
    const float* __restrict__ ba1, const float* __restrict__ Wa2,
    const float* __restrict__ U, const float* __restrict__ V,
    const int* __restrict__ srcs, float* __restrict__ Lg)
{
  __shared__ int   s_src[NSLOT];
  __shared__ float s_ef[4][32];
  int b = blockIdx.x, t = threadIdx.x;
  int d = xcd_swz(b);
  int wave = t >> 6, lane = t & 63;
  int pos = d & (CHAIN-1);
  if(t < NFIX) s_src[t] = srcs[d*NFIX + t];
  if(t == NFIX)   s_src[NFIX]   = (pos > 0)       ? d-1 : d;   // self -> invalid
  if(t == NFIX+1) s_src[NFIX+1] = (pos < CHAIN-1) ? d+1 : d;   // self -> invalid
  __syncthreads();

  float tdx = trans[d*3+0], tdy = trans[d*3+1], tdz = trans[d*3+2];
  float vb0 = V[d*128 + lane], vb1 = V[d*128 + 64 + lane];
  float bbias0 = ba1[lane], bbias1 = ba1[64 + lane];

  for(int e = wave; e < NSLOT; e += 4){
    int src = s_src[e];
    float dx = trans[src*3+0]-tdx, dy = trans[src*3+1]-tdy, dz = trans[src*3+2]-tdz;
    float dist = sqrtf(dx*dx + dy*dy + dz*dz + 1e-12f);
    int valid = (dist > 1e-3f) ? 1 : 0;
    float rel = (float)(src - d);
    if(lane < 16){
      float mu = (float)lane * (20.0f/15.0f);
      float zz = (dist - mu) / 1.25f;
      s_ef[wave][lane] = expf(-(zz*zz));
    } else if(lane < 32){
      int idx = lane - 16; int j = idx & 7;
      float fr = expf((float)(2*j) * (float)(-0.5756462732485115));
      float ang = rel * fr;
      s_ef[wave][lane] = (idx < 8) ? cosf(ang) : sinf(ang);
    }
    asm volatile("s_waitcnt lgkmcnt(0)" ::: "memory");
    __builtin_amdgcn_wave_barrier();
    float h0 = bbias0 + U[src*128 + lane]      + vb0;
    float h1 = bbias1 + U[src*128 + 64 + lane] + vb1;
    for(int f=0; f<32; f++){
      float ev = s_ef[wave][f];
      h0 += ev * Wa1[(262+f)*128 + lane];
      h1 += ev * Wa1[(262+f)*128 + 64 + lane];
    }
    h0 = (h0 >= 0.0f) ? h0 : 0.01f*h0;
    h1 = (h1 >= 0.0f) ? h1 : 0.01f*h1;
    for(int h=0; h<8; h++){
      float part = h0 * Wa2[lane*8 + h] + h1 * Wa2[(64+lane)*8 + h];
      for(int off=32; off; off>>=1) part += __shfl_xor(part, off, 64);
      if(lane == 0) Lg[(d*NSLOT + e)*8 + h] = valid ? part : -1e30f;
    }
  }
}

// ---------------- K4: softmax + agg + @Wo -> Y ------------
__global__ __launch_bounds__(256) void k_aggWo(
    const float* __restrict__ P, const float* __restrict__ Wo,
    const int* __restrict__ srcs, const float* __restrict__ Lg,
    float* __restrict__ Y)
{
  __shared__ int   s_src[NSLOT];
  __shared__ float s_att[NSLOT*8];
  __shared__ float s_agg[4][256];
  int b = blockIdx.x, t = threadIdx.x;
  int d = xcd_swz(b);
  int pos = d & (CHAIN-1);
  if(t < NFIX) s_src[t] = srcs[d*NFIX + t];
  if(t == NFIX)   s_src[NFIX]   = (pos > 0)       ? d-1 : d;
  if(t == NFIX+1) s_src[NFIX+1] = (pos < CHAIN-1) ? d+1 : d;
  for(int i=t; i<NSLOT*8; i+=256) s_att[i] = Lg[d*NSLOT*8 + i];
  __syncthreads();

  if(t < 64){   // wave-parallel softmax: lane = (group g = t>>3, head h = t&7)
    int h = t & 7, g = t >> 3;
    float m = -INFINITY;
    for(int e=g; e<NSLOT; e+=8) m = fmaxf(m, s_att[e*8+h]);
    for(int off=8; off<64; off<<=1) m = fmaxf(m, __shfl_xor(m, off, 64));
    m = (m > -5e29f) ? m : 0.0f;
    float z = 0.0f;
    for(int e=g; e<NSLOT; e+=8){
      float p = expf(s_att[e*8+h] - m);   // invalid: expf(-1e30-m) == 0
      s_att[e*8+h] = p; z += p;
    }
    for(int off=8; off<64; off<<=1) z += __shfl_xor(z, off, 64);
    float den = z + 1e-9f;
    for(int e=g; e<NSLOT; e+=8) s_att[e*8+h] = s_att[e*8+h] / den;
  }
  __syncthreads();

  {
    float a0=0.f,a1=0.f,a2=0.f,a3=0.f; int h = t >> 5;
    for(int e=0;e<NSLOT;e++){
      float w = s_att[e*8 + h];
      const float* Pr = P + s_src[e]*1024 + t;
      a0 += w*Pr[0]; a1 += w*Pr[256]; a2 += w*Pr[512]; a3 += w*Pr[768];
    }
    s_agg[0][t]=a0; s_agg[1][t]=a1; s_agg[2][t]=a2; s_agg[3][t]=a3;
  }
  __syncthreads();

  {
    int o1 = t, o2 = t + 256;
    int c1 = o1 >> 7, k1 = o1 & 127, c2 = o2 >> 7, k2 = o2 & 127;
    float x1=0.f, x2=0.f;
    for(int u=0;u<256;u++){
      x1 += s_agg[c1][u] * Wo[u*128 + k1];
      x2 += s_agg[c2][u] * Wo[u*128 + k2];
    }
    Y[d*512 + c1*128 + k1] = x1;
    Y[d*512 + c2*128 + k2] = x2;
  }
}

// ---------------- K5: per-node MLP chain (2 nodes / block) ------------
__global__ __launch_bounds__(256) void k_node(
    const float* __restrict__ rots, const float* __restrict__ trans,
    const float* __restrict__ Y,
    const float* __restrict__ Wg, const float* __restrict__ Wf1,
    const float* __restrict__ Wf2, const float* __restrict__ Wr1,
    const float* __restrict__ br1, const float* __restrict__ Wr2,
    const float* __restrict__ br2, const float* __restrict__ Wr3,
    const float* __restrict__ br3, const float* __restrict__ Wt,
    const int* __restrict__ nmask, float* __restrict__ out)
{
  __shared__ float s_y[2][4][128];
  __shared__ float s_gate[2][128];
  __shared__ float s_t1[2][128];
  __shared__ float s_bb0[2][128];
  __shared__ float s_gv[2][3][128];
  __shared__ float s_h1[2][256];
  __shared__ float s_h2[2][128];
  __shared__ float s_sc[2][8];

  int b = blockIdx.x, t = threadIdx.x;
  int half = t >> 7, k = t & 127;
  int d = b*2 + half;
  for(int c=0;c<4;c++) s_y[half][c][k] = Y[d*512 + c*128 + k];
  __syncthreads();

  float g=0.f, f1=0.f;
  for(int kk=0;kk<128;kk++){
    float yv = s_y[half][0][kk];
    g  += yv * Wg[kk*128 + k];
    f1 += yv * Wf1[kk*128 + k];
  }
  s_gate[half][k] = 1.0f/(1.0f + expf(-g));
  s_t1[half][k] = fmaxf(f1, 0.0f);
  __syncthreads();

  float f0 = 0.f;
  for(int kk=0;kk<128;kk++) f0 += s_t1[half][kk] * Wf2[kk*128 + k];
  float bb0 = s_y[half][0][k] + f0;
  s_bb0[half][k] = bb0;
  out[OUT_BB + d*512 + k] = bb0;
  float gt = s_gate[half][k];
  for(int c=1;c<4;c++){
    float v = s_y[half][c][k] * gt;
    s_gv[half][c-1][k] = v;
    out[OUT_BB + d*512 + c*128 + k] = v;
  }
  __syncthreads();

  float a1 = br1[k], a2 = br1[128+k];
  for(int kk=0;kk<128;kk++){
    float bv = s_bb0[half][kk];
    a1 += bv * Wr1[kk*256 + k];
    a2 += bv * Wr1[kk*256 + 128 + k];
  }
  s_h1[half][k] = fmaxf(a1, 0.0f);
  s_h1[half][128+k] = fmaxf(a2, 0.0f);
  __syncthreads();

  float a = br2[k];
  for(int kk=0;kk<256;kk++) a += s_h1[half][kk] * Wr2[kk*128 + k];
  s_h2[half][k] = fmaxf(a, 0.0f);
  __syncthreads();

  if(k < 3){
    float q = br3[k];
    for(int kk=0;kk<128;kk++) q += s_h2[half][kk] * Wr3[kk*6 + k];
    s_sc[half][k] = q;
  } else if(k >= 4 && k < 7){
    int i = k - 4; float s = 0.f;
    for(int kk=0;kk<128;kk++) s += s_gv[half][i][kk] * Wt[kk];
    s_sc[half][4+i] = s;
  }
  __syncthreads();

  if(k == 0){
    int nz = nmask[d];
    float q1=s_sc[half][0], q2=s_sc[half][1], q3=s_sc[half][2];
    float nrm = sqrtf(1.0f + q1*q1 + q2*q2 + q3*q3);
    float w=1.0f/nrm, x=q1/nrm, y=q2/nrm, z=q3/nrm;
    float Ru[3][3];
    Ru[0][0]=1.f-2.f*(y*y+z*z); Ru[0][1]=2.f*(x*y-w*z);     Ru[0][2]=2.f*(x*z+w*y);
    Ru[1][0]=2.f*(x*y+w*z);     Ru[1][1]=1.f-2.f*(x*x+z*z); Ru[1][2]=2.f*(y*z-w*x);
    Ru[2][0]=2.f*(x*z-w*y);     Ru[2][1]=2.f*(y*z+w*x);     Ru[2][2]=1.f-2.f*(x*x+y*y);
    for(int i=0;i<3;i++){
      for(int j=0;j<3;j++){
        float rv;
        if(nz){
          rv = rots[d*9+i*3+0]*Ru[0][j] + rots[d*9+i*3+1]*Ru[1][j] + rots[d*9+i*3+2]*Ru[2][j];
        } else {
          rv = rots[d*9+i*3+j];
        }
        out[OUT_ROT + d*9 + i*3 + j] = rv;
      }
      float tv = trans[d*3+i];
      out[OUT_TRANS + d*3 + i] = nz ? (tv + s_sc[half][4+i]) : tv;
    }
  }
}

extern "C" void kernel_launch(void* const* d_in, const int* in_sizes, int n_in,
                              void* d_out, int out_size, void* d_ws, size_t ws_size,
                              hipStream_t stream)
{
  (void)in_sizes; (void)n_in; (void)out_size; (void)ws_size;
  const float* rots = (const float*)d_in[0];
  const float* trans = (const float*)d_in[1];
  const float* nf   = (const float*)d_in[2];
  const float* Wa1  = (const float*)d_in[3];
  const float* ba1  = (const float*)d_in[4];
  const float* Wa2  = (const float*)d_in[5];
  const float* Wv   = (const float*)d_in[6];
  const float* Wo   = (const float*)d_in[7];
  const float* Wg   = (const float*)d_in[8];
  const float* Wf1  = (const float*)d_in[9];
  const float* Wf2  = (const float*)d_in[10];
  const float* Wr1  = (const float*)d_in[11];
  const float* br1  = (const float*)d_in[12];
  const float* Wr2  = (const float*)d_in[13];
  const float* br2  = (const float*)d_in[14];
  const float* Wr3  = (const float*)d_in[15];
  const float* br3  = (const float*)d_in[16];
  const float* Wt   = (const float*)d_in[17];
  const int* xmask  = (const int*)d_in[19];
  const int* nmask  = (const int*)d_in[20];

  float* P = (float*)d_ws;                 // NN*1024 f32  (8 MB)
  float* U = P + NN*1024;                  // NN*128       (1 MB)
  float* V = U + NN*128;                   // NN*128       (1 MB)
  int* srcs = (int*)(V + NN*128);          // NN*40 int    (320 KB)
  float* Lg = (float*)(srcs + NN*NFIX);    // NN*42*8 f32  (2.75 MB)
  float* Y  = Lg + NN*NSLOT*8;             // NN*512 f32   (4 MB)

  k_prep<<<NN, 256, 0, stream>>>(rots, trans, nf, Wa1, Wv, xmask, nmask, P, U, V);
  k_topk<<<NN, 64, 0, stream>>>(trans, srcs);
  k_edge<<<NN, 256, 0, stream>>>(trans, Wa1, ba1, Wa2, U, V, srcs, Lg);
  k_aggWo<<<NN, 256, 0, stream>>>(P, Wo, srcs, Lg, Y);
  k_node<<<NN/2, 256, 0, stream>>>(rots, trans, Y, Wg, Wf1, Wf2,
                                   Wr1, br1, Wr2, br2, Wr3, br3, Wt,
                                   nmask, (float*)d_out);
}

// Round 3
// 260.185 us; speedup vs baseline: 1.8948x; 1.6884x over previous
//
#include <hip/hip_runtime.h>
#include <hip/hip_bf16.h>
#include <math.h>

#define NN 2048
#define CHAIN 512
#define KNN 30
#define LRK 10
#define NFIX 40
#define NSLOT 42
#define HPAD 132

#define OUT_ROT 0
#define OUT_TRANS (NN*9)
#define OUT_BB (NN*9 + NN*3)

#define THREEFRY_PARTITIONABLE 1

__device__ __forceinline__ int xcd_swz(int b){ return ((b & 7) << 8) | (b >> 3); }

// ---------------- threefry2x32, key = (0, 42) ----------------
__device__ __forceinline__ unsigned rotl32(unsigned x, unsigned r){ return (x<<r)|(x>>(32u-r)); }

__device__ __forceinline__ void tf_block(unsigned &x0, unsigned &x1){
  const unsigned k0 = 0u, k1 = 42u, k2 = 0x1BD11BDAu ^ 0u ^ 42u;
  x0 += k0; x1 += k1;
#define TFR(a) x0 += x1; x1 = rotl32(x1,(a)); x1 ^= x0;
  TFR(13) TFR(15) TFR(26) TFR(6)   x0 += k1; x1 += k2 + 1u;
  TFR(17) TFR(29) TFR(16) TFR(24)  x0 += k2; x1 += k0 + 2u;
  TFR(13) TFR(15) TFR(26) TFR(6)   x0 += k0; x1 += k1 + 3u;
  TFR(17) TFR(29) TFR(16) TFR(24)  x0 += k1; x1 += k2 + 4u;
  TFR(13) TFR(15) TFR(26) TFR(6)   x0 += k2; x1 += k0 + 5u;
#undef TFR
}

__device__ __forceinline__ float gumbel_from_bits(unsigned bits){
  float f = __uint_as_float((bits >> 9) | 0x3f800000u) - 1.0f;
  const float tiny = 1.17549435e-38f;
  float u = fmaxf(tiny, f * (1.0f - tiny) + tiny);
  return -logf(-logf(u));
}

__device__ __forceinline__ float gumbel_at(unsigned p){
#if THREEFRY_PARTITIONABLE
  unsigned x0 = 0u, x1 = p;
  tf_block(x0, x1);
  return gumbel_from_bits(x0 ^ x1);
#else
  const unsigned HALF = (NN*(unsigned)NN)/2u;
  unsigned c0, c1; bool lo = p < HALF;
  if(lo){ c0 = p; c1 = p + HALF; } else { c0 = p - HALF; c1 = p; }
  tf_block(c0, c1);
  return gumbel_from_bits(lo ? c0 : c1);
#endif
}

// ---------------- K1: per-node prep ----------------
__global__ __launch_bounds__(256) void k_prep(
    const float* __restrict__ rots, const float* __restrict__ trans,
    const float* __restrict__ nf, const float* __restrict__ Wa1,
    const float* __restrict__ Wv, const int* __restrict__ xmask,
    const int* __restrict__ nmask,
    float* __restrict__ P, float* __restrict__ U, float* __restrict__ V)
{
  __shared__ float fr[4][132];
  int n = blockIdx.x, t = threadIdx.x;
  if(t < 128){
    fr[0][t] = nf[n*512 + t];
    fr[1][t] = nf[n*512 + 128 + t];
    fr[2][t] = nf[n*512 + 256 + t];
    fr[3][t] = nf[n*512 + 384 + t];
  } else if(t == 128){
    fr[0][128] = 0.0f; fr[0][129] = 0.0f;
    fr[0][130] = (nmask[n] != 0 && xmask[n] == 0) ? 1.0f : 0.0f;
  } else if(t >= 160 && t < 169){
    int q = t - 160; int a = q / 3, i = q % 3;
    const float BB[3][3] = {{-0.525f,1.363f,0.0f},{0.f,0.f,0.f},{1.526f,0.f,0.f}};
    float bb = rots[n*9+i*3+0]*BB[a][0] + rots[n*9+i*3+1]*BB[a][1]
             + rots[n*9+i*3+2]*BB[a][2] + trans[n*3+i];
    fr[1+i][128+a] = bb;
  }
  __syncthreads();
  float a0=0.f,a1=0.f,a2=0.f,a3=0.f;
  for(int j=0;j<131;j++){
    float w = Wv[j*256 + t];
    a0 += fr[0][j]*w; a1 += fr[1][j]*w; a2 += fr[2][j]*w; a3 += fr[3][j]*w;
  }
  P[n*1024       + t] = a0;
  P[n*1024 + 256 + t] = a1;
  P[n*1024 + 512 + t] = a2;
  P[n*1024 + 768 + t] = a3;
  if(t < 128){
    float s = 0.f;
    for(int j=0;j<131;j++) s += fr[0][j]*Wa1[j*128 + t];
    U[n*128 + t] = s;
  } else {
    int k = t - 128; float s = 0.f;
    for(int j=0;j<131;j++) s += fr[0][j]*Wa1[(131+j)*128 + k];
    V[n*128 + k] = s;
  }
}

// ---------------- K2: per-row top-30 (knn) + top-10 (lr) ---------
__global__ __launch_bounds__(64) void k_topk(
    const float* __restrict__ trans, int* __restrict__ srcs)
{
  __shared__ float d2s[NN];
  __shared__ float scs[NN];
  int i = blockIdx.x; int lane = threadIdx.x;
  float tx = trans[i*3+0], ty = trans[i*3+1], tz = trans[i*3+2];
  int ci = i >> 9;
  for(int j=lane;j<NN;j+=64){
    float dx = __fsub_rn(trans[j*3+0], tx);
    float dy = __fsub_rn(trans[j*3+1], ty);
    float dz = __fsub_rn(trans[j*3+2], tz);
    float d2 = __fadd_rn(__fadd_rn(__fmul_rn(dx,dx),__fmul_rn(dy,dy)),__fmul_rn(dz,dz));
    bool val = ((j>>9) == ci) && (j != i);
    float dm = val ? d2 : 1e30f;
    d2s[j] = dm;
    float g = gumbel_at((unsigned)(i*NN + j));
    scs[j] = __fadd_rn(__fmul_rn(-1.5f, logf(dm)), g);
  }
  __syncthreads();
  unsigned long long best = ~0ull;
  for(int j=lane;j<NN;j+=64){
    unsigned long long kk = ((unsigned long long)__float_as_uint(d2s[j])<<32) | (unsigned)j;
    if(kk < best) best = kk;
  }
  for(int k=0;k<KNN;k++){
    unsigned long long r = best;
    for(int off=32; off; off>>=1){
      unsigned long long o = __shfl_xor(r, off, 64);
      if(o < r) r = o;
    }
    int win = (int)(unsigned)(r & 0xffffffffull);
    if(lane == 0){ srcs[i*NFIX + k] = win; d2s[win] = __uint_as_float(0x7f800000u); }
    __syncthreads();
    if((win & 63) == lane){
      best = ~0ull;
      for(int j=lane;j<NN;j+=64){
        unsigned long long kk = ((unsigned long long)__float_as_uint(d2s[j])<<32) | (unsigned)j;
        if(kk < best) best = kk;
      }
    }
  }
  unsigned long long bmax = 0ull;
  for(int j=lane;j<NN;j+=64){
    unsigned b = __float_as_uint(scs[j]);
    unsigned ord = b ^ ((b & 0x80000000u) ? 0xFFFFFFFFu : 0x80000000u);
    unsigned long long kk = ((unsigned long long)ord<<32) | (unsigned)(NN-1-j);
    if(kk > bmax) bmax = kk;
  }
  for(int k=0;k<LRK;k++){
    unsigned long long r = bmax;
    for(int off=32; off; off>>=1){
      unsigned long long o = __shfl_xor(r, off, 64);
      if(o > r) r = o;
    }
    int win = NN-1 - (int)(unsigned)(r & 0xffffffffull);
    if(lane == 0){ srcs[i*NFIX + KNN + k] = win; scs[win] = __uint_as_float(0xFF800000u); }
    __syncthreads();
    if((win & 63) == lane){
      bmax = 0ull;
      for(int j=lane;j<NN;j+=64){
        unsigned b = __float_as_uint(scs[j]);
        unsigned ord = b ^ ((b & 0x80000000u) ? 0xFFFFFFFFu : 0x80000000u);
        unsigned long long kk = ((unsigned long long)ord<<32) | (unsigned)(NN-1-j);
        if(kk > bmax) bmax = kk;
      }
    }
  }
}

// ---------------- K3: edge logits + softmax + agg + @Wo (fused, stage-parallel) ----
__global__ __launch_bounds__(256) void k_attn(
    const float* __restrict__ trans, const float* __restrict__ Wa1,
    const float* __restrict__ ba1, const float* __restrict__ Wa2,
    const float* __restrict__ Wo,
    const float* __restrict__ U, const float* __restrict__ V,
    const float* __restrict__ P,
    const int* __restrict__ srcs, float* __restrict__ Y)
{
  __shared__ int   s_src[NSLOT];
  __shared__ int   s_val[NSLOT];
  __shared__ float s_dist[NSLOT];
  __shared__ float s_rel[NSLOT];
  __shared__ float s_ef[NSLOT*32];
  __shared__ __align__(16) float s_H[NSLOT*HPAD];
  __shared__ __align__(16) float s_wa2t[8*HPAD];
  __shared__ float s_att[NSLOT*8];
  __shared__ float s_agg[4][256];

  int b = blockIdx.x, t = threadIdx.x;
  int d = xcd_swz(b);
  int wave = t >> 6, lane = t & 63;
  int pos = d & (CHAIN-1);

  // ---- stage 0: srcs, dist, rel, valid (42 threads) ----
  if(t < NSLOT){
    int src;
    if(t < NFIX)      src = srcs[d*NFIX + t];
    else if(t == NFIX) src = (pos > 0)       ? d-1 : d;
    else               src = (pos < CHAIN-1) ? d+1 : d;
    s_src[t] = src;
    float dx = trans[src*3+0]-trans[d*3+0];
    float dy = trans[src*3+1]-trans[d*3+1];
    float dz = trans[src*3+2]-trans[d*3+2];
    float dist = sqrtf(dx*dx + dy*dy + dz*dz + 1e-12f);
    s_dist[t] = dist;
    s_rel[t] = (float)(src - d);
    s_val[t] = (dist > 1e-3f) ? 1 : 0;
  }
  // Wa2 transpose load: s_wa2t[h][k] = Wa2[k*8+h]
  for(int i=t; i<1024; i+=256){
    int k = i >> 3, h = i & 7;
    s_wa2t[h*HPAD + k] = Wa2[i];
  }
  __syncthreads();

  // ---- stage 1: ef[42][32] fully parallel ----
  for(int i=t; i<NSLOT*32; i+=256){
    int e = i >> 5, f = i & 31;
    float v;
    if(f < 16){
      float zz = (s_dist[e] - (float)f * (20.0f/15.0f)) * 0.8f;
      v = expf(-(zz*zz));
    } else {
      int idx = f - 16; int j = idx & 7;
      float fr = expf((float)(2*j) * (float)(-0.5756462732485115));
      float ang = s_rel[e] * fr;
      v = (idx < 8) ? cosf(ang) : sinf(ang);
    }
    s_ef[i] = v;
  }
  __syncthreads();

  // ---- stage 2: H[e][0..127] = leaky(U[src]+V[d]+ef@Wa1ef+ba1); no inner barriers ----
  {
    float vb0 = V[d*128 + lane], vb1 = V[d*128 + 64 + lane];
    float bb0 = ba1[lane], bb1 = ba1[64 + lane];
    for(int e = wave; e < NSLOT; e += 4){
      int src = s_src[e];
      float h0 = bb0 + vb0 + U[src*128 + lane];
      float h1 = bb1 + vb1 + U[src*128 + 64 + lane];
      for(int f=0; f<32; f++){
        float ev = s_ef[e*32 + f];
        h0 += ev * Wa1[(262+f)*128 + lane];
        h1 += ev * Wa1[(262+f)*128 + 64 + lane];
      }
      h0 = (h0 >= 0.0f) ? h0 : 0.01f*h0;
      h1 = (h1 >= 0.0f) ? h1 : 0.01f*h1;
      s_H[e*HPAD + lane] = h0;
      s_H[e*HPAD + 64 + lane] = h1;
    }
  }
  __syncthreads();

  // ---- stage 3: logits[e][h] = H[e] . Wa2[:,h]  (336 independent dots) ----
  for(int p = t; p < NSLOT*8; p += 256){
    int e = p >> 3, h = p & 7;
    const float4* Hp = (const float4*)(s_H + e*HPAD);
    const float4* Wp = (const float4*)(s_wa2t + h*HPAD);
    float acc = 0.f;
#pragma unroll
    for(int q=0; q<32; q++){
      float4 a = Hp[q], w = Wp[q];
      acc += a.x*w.x + a.y*w.y + a.z*w.z + a.w*w.w;
    }
    s_att[p] = s_val[e] ? acc : -1e30f;
  }
  __syncthreads();

  // ---- stage 4: per-head softmax (one wave) ----
  if(t < 64){
    int h = t & 7, g = t >> 3;
    float m = -INFINITY;
    for(int e=g; e<NSLOT; e+=8) m = fmaxf(m, s_att[e*8+h]);
    for(int off=8; off<64; off<<=1) m = fmaxf(m, __shfl_xor(m, off, 64));
    m = (m > -5e29f) ? m : 0.0f;
    float z = 0.0f;
    for(int e=g; e<NSLOT; e+=8){
      float p = expf(s_att[e*8+h] - m);
      s_att[e*8+h] = p; z += p;
    }
    for(int off=8; off<64; off<<=1) z += __shfl_xor(z, off, 64);
    float den = z + 1e-9f;
    for(int e=g; e<NSLOT; e+=8) s_att[e*8+h] = s_att[e*8+h] / den;
  }
  __syncthreads();

  // ---- stage 5: agg[c][u] = sum_e attn[e][u>>5] * P[src][c][u] ----
  {
    float a0=0.f,a1=0.f,a2=0.f,a3=0.f; int h = t >> 5;
    for(int e=0;e<NSLOT;e++){
      float w = s_att[e*8 + h];
      const float* Pr = P + s_src[e]*1024 + t;
      a0 += w*Pr[0]; a1 += w*Pr[256]; a2 += w*Pr[512]; a3 += w*Pr[768];
    }
    s_agg[0][t]=a0; s_agg[1][t]=a1; s_agg[2][t]=a2; s_agg[3][t]=a3;
  }
  __syncthreads();

  // ---- stage 6: Y = agg @ Wo ----
  {
    int o1 = t, o2 = t + 256;
    int c1 = o1 >> 7, k1 = o1 & 127, c2 = o2 >> 7, k2 = o2 & 127;
    float x1=0.f, x2=0.f;
    for(int u=0;u<256;u++){
      x1 += s_agg[c1][u] * Wo[u*128 + k1];
      x2 += s_agg[c2][u] * Wo[u*128 + k2];
    }
    Y[d*512 + c1*128 + k1] = x1;
    Y[d*512 + c2*128 + k2] = x2;
  }
}

// ---------------- K5: per-node MLP chain (2 nodes / block) ------------
__global__ __launch_bounds__(256) void k_node(
    const float* __restrict__ rots, const float* __restrict__ trans,
    const float* __restrict__ Y,
    const float* __restrict__ Wg, const float* __restrict__ Wf1,
    const float* __restrict__ Wf2, const float* __restrict__ Wr1,
    const float* __restrict__ br1, const float* __restrict__ Wr2,
    const float* __restrict__ br2, const float* __restrict__ Wr3,
    const float* __restrict__ br3, const float* __restrict__ Wt,
    const int* __restrict__ nmask, float* __restrict__ out)
{
  __shared__ float s_y[2][4][128];
  __shared__ float s_gate[2][128];
  __shared__ float s_t1[2][128];
  __shared__ float s_bb0[2][128];
  __shared__ float s_gv[2][3][128];
  __shared__ float s_h1[2][256];
  __shared__ float s_h2[2][128];
  __shared__ float s_sc[2][8];

  int b = blockIdx.x, t = threadIdx.x;
  int half = t >> 7, k = t & 127;
  int d = b*2 + half;
  for(int c=0;c<4;c++) s_y[half][c][k] = Y[d*512 + c*128 + k];
  __syncthreads();

  float g=0.f, f1=0.f;
  for(int kk=0;kk<128;kk++){
    float yv = s_y[half][0][kk];
    g  += yv * Wg[kk*128 + k];
    f1 += yv * Wf1[kk*128 + k];
  }
  s_gate[half][k] = 1.0f/(1.0f + expf(-g));
  s_t1[half][k] = fmaxf(f1, 0.0f);
  __syncthreads();

  float f0 = 0.f;
  for(int kk=0;kk<128;kk++) f0 += s_t1[half][kk] * Wf2[kk*128 + k];
  float bb0 = s_y[half][0][k] + f0;
  s_bb0[half][k] = bb0;
  out[OUT_BB + d*512 + k] = bb0;
  float gt = s_gate[half][k];
  for(int c=1;c<4;c++){
    float v = s_y[half][c][k] * gt;
    s_gv[half][c-1][k] = v;
    out[OUT_BB + d*512 + c*128 + k] = v;
  }
  __syncthreads();

  float a1 = br1[k], a2 = br1[128+k];
  for(int kk=0;kk<128;kk++){
    float bv = s_bb0[half][kk];
    a1 += bv * Wr1[kk*256 + k];
    a2 += bv * Wr1[kk*256 + 128 + k];
  }
  s_h1[half][k] = fmaxf(a1, 0.0f);
  s_h1[half][128+k] = fmaxf(a2, 0.0f);
  __syncthreads();

  float a = br2[k];
  for(int kk=0;kk<256;kk++) a += s_h1[half][kk] * Wr2[kk*128 + k];
  s_h2[half][k] = fmaxf(a, 0.0f);
  __syncthreads();

  if(k < 3){
    float q = br3[k];
    for(int kk=0;kk<128;kk++) q += s_h2[half][kk] * Wr3[kk*6 + k];
    s_sc[half][k] = q;
  } else if(k >= 4 && k < 7){
    int i = k - 4; float s = 0.f;
    for(int kk=0;kk<128;kk++) s += s_gv[half][i][kk] * Wt[kk];
    s_sc[half][4+i] = s;
  }
  __syncthreads();

  if(k == 0){
    int nz = nmask[d];
    float q1=s_sc[half][0], q2=s_sc[half][1], q3=s_sc[half][2];
    float nrm = sqrtf(1.0f + q1*q1 + q2*q2 + q3*q3);
    float w=1.0f/nrm, x=q1/nrm, y=q2/nrm, z=q3/nrm;
    float Ru[3][3];
    Ru[0][0]=1.f-2.f*(y*y+z*z); Ru[0][1]=2.f*(x*y-w*z);     Ru[0][2]=2.f*(x*z+w*y);
    Ru[1][0]=2.f*(x*y+w*z);     Ru[1][1]=1.f-2.f*(x*x+z*z); Ru[1][2]=2.f*(y*z-w*x);
    Ru[2][0]=2.f*(x*z-w*y);     Ru[2][1]=2.f*(y*z+w*x);     Ru[2][2]=1.f-2.f*(x*x+y*y);
    for(int i=0;i<3;i++){
      for(int j=0;j<3;j++){
        float rv;
        if(nz){
          rv = rots[d*9+i*3+0]*Ru[0][j] + rots[d*9+i*3+1]*Ru[1][j] + rots[d*9+i*3+2]*Ru[2][j];
        } else {
          rv = rots[d*9+i*3+j];
        }
        out[OUT_ROT + d*9 + i*3 + j] = rv;
      }
      float tv = trans[d*3+i];
      out[OUT_TRANS + d*3 + i] = nz ? (tv + s_sc[half][4+i]) : tv;
    }
  }
}

extern "C" void kernel_launch(void* const* d_in, const int* in_sizes, int n_in,
                              void* d_out, int out_size, void* d_ws, size_t ws_size,
                              hipStream_t stream)
{
  (void)in_sizes; (void)n_in; (void)out_size; (void)ws_size;
  const float* rots = (const float*)d_in[0];
  const float* trans = (const float*)d_in[1];
  const float* nf   = (const float*)d_in[2];
  const float* Wa1  = (const float*)d_in[3];
  const float* ba1  = (const float*)d_in[4];
  const float* Wa2  = (const float*)d_in[5];
  const float* Wv   = (const float*)d_in[6];
  const float* Wo   = (const float*)d_in[7];
  const float* Wg   = (const float*)d_in[8];
  const float* Wf1  = (const float*)d_in[9];
  const float* Wf2  = (const float*)d_in[10];
  const float* Wr1  = (const float*)d_in[11];
  const float* br1  = (const float*)d_in[12];
  const float* Wr2  = (const float*)d_in[13];
  const float* br2  = (const float*)d_in[14];
  const float* Wr3  = (const float*)d_in[15];
  const float* br3  = (const float*)d_in[16];
  const float* Wt   = (const float*)d_in[17];
  const int* xmask  = (const int*)d_in[19];
  const int* nmask  = (const int*)d_in[20];

  float* P = (float*)d_ws;                 // NN*1024 f32  (8 MB)
  float* U = P + NN*1024;                  // NN*128       (1 MB)
  float* V = U + NN*128;                   // NN*128       (1 MB)
  int* srcs = (int*)(V + NN*128);          // NN*40 int    (320 KB)
  float* Y  = (float*)(srcs + NN*NFIX);    // NN*512 f32   (4 MB)

  k_prep<<<NN, 256, 0, stream>>>(rots, trans, nf, Wa1, Wv, xmask, nmask, P, U, V);
  k_topk<<<NN, 64, 0, stream>>>(trans, srcs);
  k_attn<<<NN, 256, 0, stream>>>(trans, Wa1, ba1, Wa2, Wo, U, V, P, srcs, Y);
  k_node<<<NN/2, 256, 0, stream>>>(rots, trans, Y, Wg, Wf1, Wf2,
                                   Wr1, br1, Wr2, br2, Wr3, br3, Wt,
                                   nmask, (float*)d_out);
}

// Round 4
// 175.115 us; speedup vs baseline: 2.8152x; 1.4858x over previous
//
#include <hip/hip_runtime.h>
#include <hip/hip_bf16.h>
#include <math.h>

#define NN 2048
#define CHAIN 512
#define KNN 30
#define LRK 10
#define NFIX 40
#define NSLOT 42
#define HPAD 132

#define OUT_ROT 0
#define OUT_TRANS (NN*9)
#define OUT_BB (NN*9 + NN*3)

#define THREEFRY_PARTITIONABLE 1

__device__ __forceinline__ int xcd_swz(int b){ return ((b & 7) << 8) | (b >> 3); }

// ---------------- threefry2x32, key = (0, 42) ----------------
__device__ __forceinline__ unsigned rotl32(unsigned x, unsigned r){ return (x<<r)|(x>>(32u-r)); }

__device__ __forceinline__ void tf_block(unsigned &x0, unsigned &x1){
  const unsigned k0 = 0u, k1 = 42u, k2 = 0x1BD11BDAu ^ 0u ^ 42u;
  x0 += k0; x1 += k1;
#define TFR(a) x0 += x1; x1 = rotl32(x1,(a)); x1 ^= x0;
  TFR(13) TFR(15) TFR(26) TFR(6)   x0 += k1; x1 += k2 + 1u;
  TFR(17) TFR(29) TFR(16) TFR(24)  x0 += k2; x1 += k0 + 2u;
  TFR(13) TFR(15) TFR(26) TFR(6)   x0 += k0; x1 += k1 + 3u;
  TFR(17) TFR(29) TFR(16) TFR(24)  x0 += k1; x1 += k2 + 4u;
  TFR(13) TFR(15) TFR(26) TFR(6)   x0 += k2; x1 += k0 + 5u;
#undef TFR
}

__device__ __forceinline__ float gumbel_from_bits(unsigned bits){
  float f = __uint_as_float((bits >> 9) | 0x3f800000u) - 1.0f;
  const float tiny = 1.17549435e-38f;
  float u = fmaxf(tiny, f * (1.0f - tiny) + tiny);
  return -logf(-logf(u));
}

__device__ __forceinline__ float gumbel_at(unsigned p){
#if THREEFRY_PARTITIONABLE
  unsigned x0 = 0u, x1 = p;
  tf_block(x0, x1);
  return gumbel_from_bits(x0 ^ x1);
#else
  const unsigned HALF = (NN*(unsigned)NN)/2u;
  unsigned c0, c1; bool lo = p < HALF;
  if(lo){ c0 = p; c1 = p + HALF; } else { c0 = p - HALF; c1 = p; }
  tf_block(c0, c1);
  return gumbel_from_bits(lo ? c0 : c1);
#endif
}

// ---------------- K1: per-node prep ----------------
__global__ __launch_bounds__(256) void k_prep(
    const float* __restrict__ rots, const float* __restrict__ trans,
    const float* __restrict__ nf, const float* __restrict__ Wa1,
    const float* __restrict__ Wv, const int* __restrict__ xmask,
    const int* __restrict__ nmask,
    float* __restrict__ P, float* __restrict__ U, float* __restrict__ V)
{
  __shared__ float fr[4][132];
  int n = blockIdx.x, t = threadIdx.x;
  if(t < 128){
    fr[0][t] = nf[n*512 + t];
    fr[1][t] = nf[n*512 + 128 + t];
    fr[2][t] = nf[n*512 + 256 + t];
    fr[3][t] = nf[n*512 + 384 + t];
  } else if(t == 128){
    fr[0][128] = 0.0f; fr[0][129] = 0.0f;
    fr[0][130] = (nmask[n] != 0 && xmask[n] == 0) ? 1.0f : 0.0f;
  } else if(t >= 160 && t < 169){
    int q = t - 160; int a = q / 3, i = q % 3;
    const float BB[3][3] = {{-0.525f,1.363f,0.0f},{0.f,0.f,0.f},{1.526f,0.f,0.f}};
    float bb = rots[n*9+i*3+0]*BB[a][0] + rots[n*9+i*3+1]*BB[a][1]
             + rots[n*9+i*3+2]*BB[a][2] + trans[n*3+i];
    fr[1+i][128+a] = bb;
  }
  __syncthreads();
  float a0=0.f,a1=0.f,a2=0.f,a3=0.f;
  for(int j=0;j<131;j++){
    float w = Wv[j*256 + t];
    a0 += fr[0][j]*w; a1 += fr[1][j]*w; a2 += fr[2][j]*w; a3 += fr[3][j]*w;
  }
  P[n*1024       + t] = a0;
  P[n*1024 + 256 + t] = a1;
  P[n*1024 + 512 + t] = a2;
  P[n*1024 + 768 + t] = a3;
  if(t < 128){
    float s = 0.f;
    for(int j=0;j<131;j++) s += fr[0][j]*Wa1[j*128 + t];
    U[n*128 + t] = s;
  } else {
    int k = t - 128; float s = 0.f;
    for(int j=0;j<131;j++) s += fr[0][j]*Wa1[(131+j)*128 + k];
    V[n*128 + k] = s;
  }
}

// ---------------- K2: fused score + top-30/top-10 over the 512 same-chain candidates
// Cross-chain candidates have d2m=1e30 -> knn key ~max (511 valid smaller ones exist)
// and lr score <= -87 vs valid >= -16 -> provably never selected; skip them.
__global__ __launch_bounds__(128) void k_topk2(
    const float* __restrict__ trans, int* __restrict__ srcs)
{
  __shared__ unsigned s_kk[CHAIN];  // ordered d2 (ascending)
  __shared__ unsigned s_lk[CHAIN];  // flipped ordered score (ascending = best score first)
  int i = blockIdx.x, t = threadIdx.x;
  int base = (i >> 9) << 9;
  float tx = trans[i*3+0], ty = trans[i*3+1], tz = trans[i*3+2];
  for(int q=t; q<CHAIN; q+=128){
    int j = base + q;
    float dx = __fsub_rn(trans[j*3+0], tx);
    float dy = __fsub_rn(trans[j*3+1], ty);
    float dz = __fsub_rn(trans[j*3+2], tz);
    float d2 = __fadd_rn(__fadd_rn(__fmul_rn(dx,dx),__fmul_rn(dy,dy)),__fmul_rn(dz,dz));
    bool val = (j != i);
    float dm = val ? d2 : 1e30f;
    s_kk[q] = __float_as_uint(dm) ^ 0x80000000u;   // dm > 0 -> sign bit 0
    if(val){
      float g = gumbel_at((unsigned)(i*NN + j));
      float sc = __fadd_rn(__fmul_rn(-1.5f, logf(dm)), g);
      unsigned b = __float_as_uint(sc);
      unsigned ord = b ^ ((b & 0x80000000u) ? 0xFFFFFFFFu : 0x80000000u);
      s_lk[q] = ~ord;                               // smallest = largest score
    } else {
      s_lk[q] = 0xFFFFFFFFu;
    }
  }
  __syncthreads();

  int w = t >> 6, lane = t & 63;
  unsigned* arr = w ? s_lk : s_kk;
  int K = w ? LRK : KNN;
  int outoff = w ? KNN : 0;

  unsigned long long best = ~0ull;
  for(int q=lane; q<CHAIN; q+=64){
    unsigned long long kk = ((unsigned long long)arr[q]<<32) | (unsigned)q;
    if(kk < best) best = kk;
  }
  for(int k=0;k<K;k++){
    unsigned long long r = best;
    for(int off=32; off; off>>=1){
      unsigned long long o = __shfl_xor(r, off, 64);
      if(o < r) r = o;
    }
    int winq = (int)(unsigned)(r & 0xffffffffull);
    if(lane == 0){
      srcs[i*NFIX + outoff + k] = base + winq;
      arr[winq] = 0xFFFFFFFFu;
    }
    asm volatile("s_waitcnt lgkmcnt(0)" ::: "memory");
    __builtin_amdgcn_wave_barrier();
    if((winq & 63) == lane){
      best = ~0ull;
      for(int q=lane; q<CHAIN; q+=64){
        unsigned long long kk = ((unsigned long long)arr[q]<<32) | (unsigned)q;
        if(kk < best) best = kk;
      }
    }
  }
}

// ---------------- K3: edge logits + softmax + agg + @Wo (fused, stage-parallel) ----
__global__ __launch_bounds__(256) void k_attn(
    const float* __restrict__ trans, const float* __restrict__ Wa1,
    const float* __restrict__ ba1, const float* __restrict__ Wa2,
    const float* __restrict__ Wo,
    const float* __restrict__ U, const float* __restrict__ V,
    const float* __restrict__ P,
    const int* __restrict__ srcs, float* __restrict__ Y)
{
  __shared__ int   s_src[NSLOT];
  __shared__ int   s_val[NSLOT];
  __shared__ float s_dist[NSLOT];
  __shared__ float s_rel[NSLOT];
  __shared__ float s_ef[NSLOT*32];
  __shared__ __align__(16) float s_H[NSLOT*HPAD];
  __shared__ __align__(16) float s_wa2t[8*HPAD];
  __shared__ float s_att[NSLOT*8];
  __shared__ float s_agg[4][256];

  int b = blockIdx.x, t = threadIdx.x;
  int d = xcd_swz(b);
  int wave = t >> 6, lane = t & 63;
  int pos = d & (CHAIN-1);

  if(t < NSLOT){
    int src;
    if(t < NFIX)      src = srcs[d*NFIX + t];
    else if(t == NFIX) src = (pos > 0)       ? d-1 : d;
    else               src = (pos < CHAIN-1) ? d+1 : d;
    s_src[t] = src;
    float dx = trans[src*3+0]-trans[d*3+0];
    float dy = trans[src*3+1]-trans[d*3+1];
    float dz = trans[src*3+2]-trans[d*3+2];
    float dist = sqrtf(dx*dx + dy*dy + dz*dz + 1e-12f);
    s_dist[t] = dist;
    s_rel[t] = (float)(src - d);
    s_val[t] = (dist > 1e-3f) ? 1 : 0;
  }
  for(int i=t; i<1024; i+=256){
    int k = i >> 3, h = i & 7;
    s_wa2t[h*HPAD + k] = Wa2[i];
  }
  __syncthreads();

  for(int i=t; i<NSLOT*32; i+=256){
    int e = i >> 5, f = i & 31;
    float v;
    if(f < 16){
      float zz = (s_dist[e] - (float)f * (20.0f/15.0f)) * 0.8f;
      v = expf(-(zz*zz));
    } else {
      int idx = f - 16; int j = idx & 7;
      float fr = expf((float)(2*j) * (float)(-0.5756462732485115));
      float ang = s_rel[e] * fr;
      v = (idx < 8) ? cosf(ang) : sinf(ang);
    }
    s_ef[i] = v;
  }
  __syncthreads();

  {
    float vb0 = V[d*128 + lane], vb1 = V[d*128 + 64 + lane];
    float bb0 = ba1[lane], bb1 = ba1[64 + lane];
    for(int e = wave; e < NSLOT; e += 4){
      int src = s_src[e];
      float h0 = bb0 + vb0 + U[src*128 + lane];
      float h1 = bb1 + vb1 + U[src*128 + 64 + lane];
      for(int f=0; f<32; f++){
        float ev = s_ef[e*32 + f];
        h0 += ev * Wa1[(262+f)*128 + lane];
        h1 += ev * Wa1[(262+f)*128 + 64 + lane];
      }
      h0 = (h0 >= 0.0f) ? h0 : 0.01f*h0;
      h1 = (h1 >= 0.0f) ? h1 : 0.01f*h1;
      s_H[e*HPAD + lane] = h0;
      s_H[e*HPAD + 64 + lane] = h1;
    }
  }
  __syncthreads();

  for(int p = t; p < NSLOT*8; p += 256){
    int e = p >> 3, h = p & 7;
    const float4* Hp = (const float4*)(s_H + e*HPAD);
    const float4* Wp = (const float4*)(s_wa2t + h*HPAD);
    float acc = 0.f;
#pragma unroll
    for(int q=0; q<32; q++){
      float4 a = Hp[q], w = Wp[q];
      acc += a.x*w.x + a.y*w.y + a.z*w.z + a.w*w.w;
    }
    s_att[p] = s_val[e] ? acc : -1e30f;
  }
  __syncthreads();

  if(t < 64){
    int h = t & 7, g = t >> 3;
    float m = -INFINITY;
    for(int e=g; e<NSLOT; e+=8) m = fmaxf(m, s_att[e*8+h]);
    for(int off=8; off<64; off<<=1) m = fmaxf(m, __shfl_xor(m, off, 64));
    m = (m > -5e29f) ? m : 0.0f;
    float z = 0.0f;
    for(int e=g; e<NSLOT; e+=8){
      float p = expf(s_att[e*8+h] - m);
      s_att[e*8+h] = p; z += p;
    }
    for(int off=8; off<64; off<<=1) z += __shfl_xor(z, off, 64);
    float den = z + 1e-9f;
    for(int e=g; e<NSLOT; e+=8) s_att[e*8+h] = s_att[e*8+h] / den;
  }
  __syncthreads();

  {
    float a0=0.f,a1=0.f,a2=0.f,a3=0.f; int h = t >> 5;
    for(int e=0;e<NSLOT;e++){
      float w = s_att[e*8 + h];
      const float* Pr = P + s_src[e]*1024 + t;
      a0 += w*Pr[0]; a1 += w*Pr[256]; a2 += w*Pr[512]; a3 += w*Pr[768];
    }
    s_agg[0][t]=a0; s_agg[1][t]=a1; s_agg[2][t]=a2; s_agg[3][t]=a3;
  }
  __syncthreads();

  {
    int o1 = t, o2 = t + 256;
    int c1 = o1 >> 7, k1 = o1 & 127, c2 = o2 >> 7, k2 = o2 & 127;
    float x1=0.f, x2=0.f;
    for(int u=0;u<256;u++){
      x1 += s_agg[c1][u] * Wo[u*128 + k1];
      x2 += s_agg[c2][u] * Wo[u*128 + k2];
    }
    Y[d*512 + c1*128 + k1] = x1;
    Y[d*512 + c2*128 + k2] = x2;
  }
}

// ---------------- K5: per-node MLP chain (2 nodes / block) ------------
__global__ __launch_bounds__(256) void k_node(
    const float* __restrict__ rots, const float* __restrict__ trans,
    const float* __restrict__ Y,
    const float* __restrict__ Wg, const float* __restrict__ Wf1,
    const float* __restrict__ Wf2, const float* __restrict__ Wr1,
    const float* __restrict__ br1, const float* __restrict__ Wr2,
    const float* __restrict__ br2, const float* __restrict__ Wr3,
    const float* __restrict__ br3, const float* __restrict__ Wt,
    const int* __restrict__ nmask, float* __restrict__ out)
{
  __shared__ float s_y[2][4][128];
  __shared__ float s_gate[2][128];
  __shared__ float s_t1[2][128];
  __shared__ float s_bb0[2][128];
  __shared__ float s_gv[2][3][128];
  __shared__ float s_h1[2][256];
  __shared__ float s_h2[2][128];
  __shared__ float s_sc[2][8];

  int b = blockIdx.x, t = threadIdx.x;
  int half = t >> 7, k = t & 127;
  int d = b*2 + half;
  for(int c=0;c<4;c++) s_y[half][c][k] = Y[d*512 + c*128 + k];
  __syncthreads();

  float g=0.f, f1=0.f;
  for(int kk=0;kk<128;kk++){
    float yv = s_y[half][0][kk];
    g  += yv * Wg[kk*128 + k];
    f1 += yv * Wf1[kk*128 + k];
  }
  s_gate[half][k] = 1.0f/(1.0f + expf(-g));
  s_t1[half][k] = fmaxf(f1, 0.0f);
  __syncthreads();

  float f0 = 0.f;
  for(int kk=0;kk<128;kk++) f0 += s_t1[half][kk] * Wf2[kk*128 + k];
  float bb0 = s_y[half][0][k] + f0;
  s_bb0[half][k] = bb0;
  out[OUT_BB + d*512 + k] = bb0;
  float gt = s_gate[half][k];
  for(int c=1;c<4;c++){
    float v = s_y[half][c][k] * gt;
    s_gv[half][c-1][k] = v;
    out[OUT_BB + d*512 + c*128 + k] = v;
  }
  __syncthreads();

  float a1 = br1[k], a2 = br1[128+k];
  for(int kk=0;kk<128;kk++){
    float bv = s_bb0[half][kk];
    a1 += bv * Wr1[kk*256 + k];
    a2 += bv * Wr1[kk*256 + 128 + k];
  }
  s_h1[half][k] = fmaxf(a1, 0.0f);
  s_h1[half][128+k] = fmaxf(a2, 0.0f);
  __syncthreads();

  float a = br2[k];
  for(int kk=0;kk<256;kk++) a += s_h1[half][kk] * Wr2[kk*128 + k];
  s_h2[half][k] = fmaxf(a, 0.0f);
  __syncthreads();

  if(k < 3){
    float q = br3[k];
    for(int kk=0;kk<128;kk++) q += s_h2[half][kk] * Wr3[kk*6 + k];
    s_sc[half][k] = q;
  } else if(k >= 4 && k < 7){
    int i = k - 4; float s = 0.f;
    for(int kk=0;kk<128;kk++) s += s_gv[half][i][kk] * Wt[kk];
    s_sc[half][4+i] = s;
  }
  __syncthreads();

  if(k == 0){
    int nz = nmask[d];
    float q1=s_sc[half][0], q2=s_sc[half][1], q3=s_sc[half][2];
    float nrm = sqrtf(1.0f + q1*q1 + q2*q2 + q3*q3);
    float w=1.0f/nrm, x=q1/nrm, y=q2/nrm, z=q3/nrm;
    float Ru[3][3];
    Ru[0][0]=1.f-2.f*(y*y+z*z); Ru[0][1]=2.f*(x*y-w*z);     Ru[0][2]=2.f*(x*z+w*y);
    Ru[1][0]=2.f*(x*y+w*z);     Ru[1][1]=1.f-2.f*(x*x+z*z); Ru[1][2]=2.f*(y*z-w*x);
    Ru[2][0]=2.f*(x*z-w*y);     Ru[2][1]=2.f*(y*z+w*x);     Ru[2][2]=1.f-2.f*(x*x+y*y);
    for(int i=0;i<3;i++){
      for(int j=0;j<3;j++){
        float rv;
        if(nz){
          rv = rots[d*9+i*3+0]*Ru[0][j] + rots[d*9+i*3+1]*Ru[1][j] + rots[d*9+i*3+2]*Ru[2][j];
        } else {
          rv = rots[d*9+i*3+j];
        }
        out[OUT_ROT + d*9 + i*3 + j] = rv;
      }
      float tv = trans[d*3+i];
      out[OUT_TRANS + d*3 + i] = nz ? (tv + s_sc[half][4+i]) : tv;
    }
  }
}

extern "C" void kernel_launch(void* const* d_in, const int* in_sizes, int n_in,
                              void* d_out, int out_size, void* d_ws, size_t ws_size,
                              hipStream_t stream)
{
  (void)in_sizes; (void)n_in; (void)out_size; (void)ws_size;
  const float* rots = (const float*)d_in[0];
  const float* trans = (const float*)d_in[1];
  const float* nf   = (const float*)d_in[2];
  const float* Wa1  = (const float*)d_in[3];
  const float* ba1  = (const float*)d_in[4];
  const float* Wa2  = (const float*)d_in[5];
  const float* Wv   = (const float*)d_in[6];
  const float* Wo   = (const float*)d_in[7];
  const float* Wg   = (const float*)d_in[8];
  const float* Wf1  = (const float*)d_in[9];
  const float* Wf2  = (const float*)d_in[10];
  const float* Wr1  = (const float*)d_in[11];
  const float* br1  = (const float*)d_in[12];
  const float* Wr2  = (const float*)d_in[13];
  const float* br2  = (const float*)d_in[14];
  const float* Wr3  = (const float*)d_in[15];
  const float* br3  = (const float*)d_in[16];
  const float* Wt   = (const float*)d_in[17];
  const int* xmask  = (const int*)d_in[19];
  const int* nmask  = (const int*)d_in[20];

  float* P = (float*)d_ws;                 // NN*1024 f32  (8 MB)
  float* U = P + NN*1024;                  // NN*128       (1 MB)
  float* V = U + NN*128;                   // NN*128       (1 MB)
  int* srcs = (int*)(V + NN*128);          // NN*40 int    (320 KB)
  float* Y  = (float*)(srcs + NN*NFIX);    // NN*512 f32   (4 MB)

  k_prep<<<NN, 256, 0, stream>>>(rots, trans, nf, Wa1, Wv, xmask, nmask, P, U, V);
  k_topk2<<<NN, 128, 0, stream>>>(trans, srcs);
  k_attn<<<NN, 256, 0, stream>>>(trans, Wa1, ba1, Wa2, Wo, U, V, P, srcs, Y);
  k_node<<<NN/2, 256, 0, stream>>>(rots, trans, Y, Wg, Wf1, Wf2,
                                   Wr1, br1, Wr2, br2, Wr3, br3, Wt,
                                   nmask, (float*)d_out);
}

// Round 5
// 159.077 us; speedup vs baseline: 3.0991x; 1.1008x over previous
//
#include <hip/hip_runtime.h>
#include <hip/hip_bf16.h>
#include <math.h>

#define NN 2048
#define CHAIN 512
#define KNN 30
#define LRK 10
#define NFIX 40
#define NSLOT 42
#define HPAD 132

#define OUT_ROT 0
#define OUT_TRANS (NN*9)
#define OUT_BB (NN*9 + NN*3)

#define THREEFRY_PARTITIONABLE 1

__device__ __forceinline__ int xcd_swz(int b){ return ((b & 7) << 8) | (b >> 3); }

// ---------------- threefry2x32, key = (0, 42) ----------------
__device__ __forceinline__ unsigned rotl32(unsigned x, unsigned r){ return (x<<r)|(x>>(32u-r)); }

__device__ __forceinline__ void tf_block(unsigned &x0, unsigned &x1){
  const unsigned k0 = 0u, k1 = 42u, k2 = 0x1BD11BDAu ^ 0u ^ 42u;
  x0 += k0; x1 += k1;
#define TFR(a) x0 += x1; x1 = rotl32(x1,(a)); x1 ^= x0;
  TFR(13) TFR(15) TFR(26) TFR(6)   x0 += k1; x1 += k2 + 1u;
  TFR(17) TFR(29) TFR(16) TFR(24)  x0 += k2; x1 += k0 + 2u;
  TFR(13) TFR(15) TFR(26) TFR(6)   x0 += k0; x1 += k1 + 3u;
  TFR(17) TFR(29) TFR(16) TFR(24)  x0 += k1; x1 += k2 + 4u;
  TFR(13) TFR(15) TFR(26) TFR(6)   x0 += k2; x1 += k0 + 5u;
#undef TFR
}

__device__ __forceinline__ float gumbel_from_bits(unsigned bits){
  float f = __uint_as_float((bits >> 9) | 0x3f800000u) - 1.0f;
  const float tiny = 1.17549435e-38f;
  float u = fmaxf(tiny, f * (1.0f - tiny) + tiny);
  return -logf(-logf(u));
}

__device__ __forceinline__ float gumbel_at(unsigned p){
#if THREEFRY_PARTITIONABLE
  unsigned x0 = 0u, x1 = p;
  tf_block(x0, x1);
  return gumbel_from_bits(x0 ^ x1);
#else
  const unsigned HALF = (NN*(unsigned)NN)/2u;
  unsigned c0, c1; bool lo = p < HALF;
  if(lo){ c0 = p; c1 = p + HALF; } else { c0 = p - HALF; c1 = p; }
  tf_block(c0, c1);
  return gumbel_from_bits(lo ? c0 : c1);
#endif
}

// ---------------- K1: per-node prep, 4 nodes/block ----------------
__global__ __launch_bounds__(256) void k_prep(
    const float* __restrict__ rots, const float* __restrict__ trans,
    const float* __restrict__ nf, const float* __restrict__ Wa1,
    const float* __restrict__ Wv, const int* __restrict__ xmask,
    const int* __restrict__ nmask,
    float* __restrict__ P, float* __restrict__ U, float* __restrict__ V)
{
  __shared__ __align__(16) float fr[4][4][132];
  int n0 = blockIdx.x*4, t = threadIdx.x;
  for(int i=t; i<2048; i+=256){
    int nd = i>>9, c = (i>>7)&3, kk = i&127;
    fr[nd][c][kk] = nf[(n0+nd)*512 + c*128 + kk];
  }
  if(t < 4){
    fr[t][0][128] = 0.0f; fr[t][0][129] = 0.0f;
    fr[t][0][130] = (nmask[n0+t] != 0 && xmask[n0+t] == 0) ? 1.0f : 0.0f;
  } else if(t >= 16 && t < 52){
    int q = t - 16; int nd = q/9, r = q%9, a = r/3, i = r%3;
    int n = n0 + nd;
    const float BB[3][3] = {{-0.525f,1.363f,0.0f},{0.f,0.f,0.f},{1.526f,0.f,0.f}};
    float bb = rots[n*9+i*3+0]*BB[a][0] + rots[n*9+i*3+1]*BB[a][1]
             + rots[n*9+i*3+2]*BB[a][2] + trans[n*3+i];
    fr[nd][1+i][128+a] = bb;
  }
  __syncthreads();

  // P: a[nd][c], weight loaded once per 16 FMA
  float a[4][4];
#pragma unroll
  for(int nd=0;nd<4;nd++)
#pragma unroll
    for(int c=0;c<4;c++) a[nd][c]=0.f;
  for(int j=0;j<128;j+=4){
    float w0=Wv[(j+0)*256+t], w1=Wv[(j+1)*256+t], w2=Wv[(j+2)*256+t], w3=Wv[(j+3)*256+t];
#pragma unroll
    for(int nd=0;nd<4;nd++){
#pragma unroll
      for(int c=0;c<4;c++){
        float4 f4 = *(const float4*)&fr[nd][c][j];
        a[nd][c] += f4.x*w0 + f4.y*w1 + f4.z*w2 + f4.w*w3;
      }
    }
  }
  for(int j=128;j<131;j++){
    float w = Wv[j*256+t];
#pragma unroll
    for(int nd=0;nd<4;nd++)
#pragma unroll
      for(int c=0;c<4;c++) a[nd][c] += fr[nd][c][j]*w;
  }
#pragma unroll
  for(int nd=0;nd<4;nd++)
#pragma unroll
    for(int c=0;c<4;c++) P[(n0+nd)*1024 + c*256 + t] = a[nd][c];

  // U (t<128) / V (t>=128)
  int k = t & 127;
  int isV = t >> 7;
  const float* Wcol = Wa1 + (isV ? 131*128 : 0);
  float u[4] = {0.f,0.f,0.f,0.f};
  for(int j=0;j<128;j+=4){
    float w0=Wcol[(j+0)*128+k], w1=Wcol[(j+1)*128+k], w2=Wcol[(j+2)*128+k], w3=Wcol[(j+3)*128+k];
#pragma unroll
    for(int nd=0;nd<4;nd++){
      float4 f4 = *(const float4*)&fr[nd][0][j];
      u[nd] += f4.x*w0 + f4.y*w1 + f4.z*w2 + f4.w*w3;
    }
  }
  for(int j=128;j<131;j++){
    float w = Wcol[j*128+k];
#pragma unroll
    for(int nd=0;nd<4;nd++) u[nd] += fr[nd][0][j]*w;
  }
  float* OUT = isV ? V : U;
#pragma unroll
  for(int nd=0;nd<4;nd++) OUT[(n0+nd)*128 + k] = u[nd];
}

// ---------------- K2: fused score + top-30/top-10 (same-chain only) ---------
__global__ __launch_bounds__(128) void k_topk2(
    const float* __restrict__ trans, int* __restrict__ srcs)
{
  __shared__ unsigned s_kk[CHAIN];
  __shared__ unsigned s_lk[CHAIN];
  int i = blockIdx.x, t = threadIdx.x;
  int base = (i >> 9) << 9;
  float tx = trans[i*3+0], ty = trans[i*3+1], tz = trans[i*3+2];
  for(int q=t; q<CHAIN; q+=128){
    int j = base + q;
    float dx = __fsub_rn(trans[j*3+0], tx);
    float dy = __fsub_rn(trans[j*3+1], ty);
    float dz = __fsub_rn(trans[j*3+2], tz);
    float d2 = __fadd_rn(__fadd_rn(__fmul_rn(dx,dx),__fmul_rn(dy,dy)),__fmul_rn(dz,dz));
    bool val = (j != i);
    float dm = val ? d2 : 1e30f;
    s_kk[q] = __float_as_uint(dm) ^ 0x80000000u;
    if(val){
      float g = gumbel_at((unsigned)(i*NN + j));
      float sc = __fadd_rn(__fmul_rn(-1.5f, logf(dm)), g);
      unsigned b = __float_as_uint(sc);
      unsigned ord = b ^ ((b & 0x80000000u) ? 0xFFFFFFFFu : 0x80000000u);
      s_lk[q] = ~ord;
    } else {
      s_lk[q] = 0xFFFFFFFFu;
    }
  }
  __syncthreads();

  int w = t >> 6, lane = t & 63;
  unsigned* arr = w ? s_lk : s_kk;
  int K = w ? LRK : KNN;
  int outoff = w ? KNN : 0;

  unsigned long long best = ~0ull;
  for(int q=lane; q<CHAIN; q+=64){
    unsigned long long kk = ((unsigned long long)arr[q]<<32) | (unsigned)q;
    if(kk < best) best = kk;
  }
  for(int k=0;k<K;k++){
    unsigned long long r = best;
    for(int off=32; off; off>>=1){
      unsigned long long o = __shfl_xor(r, off, 64);
      if(o < r) r = o;
    }
    int winq = (int)(unsigned)(r & 0xffffffffull);
    if(lane == 0){
      srcs[i*NFIX + outoff + k] = base + winq;
      arr[winq] = 0xFFFFFFFFu;
    }
    asm volatile("s_waitcnt lgkmcnt(0)" ::: "memory");
    __builtin_amdgcn_wave_barrier();
    if((winq & 63) == lane){
      best = ~0ull;
      for(int q=lane; q<CHAIN; q+=64){
        unsigned long long kk = ((unsigned long long)arr[q]<<32) | (unsigned)q;
        if(kk < best) best = kk;
      }
    }
  }
}

// ---------------- K3: edge logits + softmax + agg + @Wo (fused) ----
__global__ __launch_bounds__(256) void k_attn(
    const float* __restrict__ trans, const float* __restrict__ Wa1,
    const float* __restrict__ ba1, const float* __restrict__ Wa2,
    const float* __restrict__ Wo,
    const float* __restrict__ U, const float* __restrict__ V,
    const float* __restrict__ P,
    const int* __restrict__ srcs, float* __restrict__ Y)
{
  __shared__ int   s_src[NSLOT];
  __shared__ int   s_val[NSLOT];
  __shared__ float s_dist[NSLOT];
  __shared__ float s_rel[NSLOT];
  __shared__ __align__(16) float s_ef[NSLOT*32];
  __shared__ __align__(16) float s_H[NSLOT*HPAD];
  __shared__ __align__(16) float s_wa2t[8*HPAD];
  __shared__ float s_att[NSLOT*8];
  __shared__ __align__(16) float s_agg[4][256];

  int b = blockIdx.x, t = threadIdx.x;
  int d = xcd_swz(b);
  int wave = t >> 6, lane = t & 63;
  int pos = d & (CHAIN-1);

  if(t < NSLOT){
    int src;
    if(t < NFIX)      src = srcs[d*NFIX + t];
    else if(t == NFIX) src = (pos > 0)       ? d-1 : d;
    else               src = (pos < CHAIN-1) ? d+1 : d;
    s_src[t] = src;
    float dx = trans[src*3+0]-trans[d*3+0];
    float dy = trans[src*3+1]-trans[d*3+1];
    float dz = trans[src*3+2]-trans[d*3+2];
    float dist = sqrtf(dx*dx + dy*dy + dz*dz + 1e-12f);
    s_dist[t] = dist;
    s_rel[t] = (float)(src - d);
    s_val[t] = (dist > 1e-3f) ? 1 : 0;
  }
  for(int i=t; i<1024; i+=256){
    int k = i >> 3, h = i & 7;
    s_wa2t[h*HPAD + k] = Wa2[i];
  }

  // hoist Wa1ef columns for this lane's two output dims into registers (loop-invariant over e)
  float wreg0[32], wreg1[32];
#pragma unroll
  for(int f=0; f<32; f++){
    wreg0[f] = Wa1[(262+f)*128 + lane];
    wreg1[f] = Wa1[(262+f)*128 + 64 + lane];
  }
  __syncthreads();

  for(int i=t; i<NSLOT*32; i+=256){
    int e = i >> 5, f = i & 31;
    float v;
    if(f < 16){
      float zz = (s_dist[e] - (float)f * (20.0f/15.0f)) * 0.8f;
      v = expf(-(zz*zz));
    } else {
      int idx = f - 16; int j = idx & 7;
      float fr = expf((float)(2*j) * (float)(-0.5756462732485115));
      float ang = s_rel[e] * fr;
      v = (idx < 8) ? cosf(ang) : sinf(ang);
    }
    s_ef[i] = v;
  }
  __syncthreads();

  {
    float vb0 = V[d*128 + lane], vb1 = V[d*128 + 64 + lane];
    float bb0 = ba1[lane], bb1 = ba1[64 + lane];
    for(int e = wave; e < NSLOT; e += 4){
      int src = s_src[e];
      float h0 = bb0 + vb0 + U[src*128 + lane];
      float h1 = bb1 + vb1 + U[src*128 + 64 + lane];
      const float4* efp = (const float4*)(s_ef + e*32);
#pragma unroll
      for(int q=0; q<8; q++){
        float4 ev = efp[q];
        h0 += ev.x*wreg0[4*q+0] + ev.y*wreg0[4*q+1] + ev.z*wreg0[4*q+2] + ev.w*wreg0[4*q+3];
        h1 += ev.x*wreg1[4*q+0] + ev.y*wreg1[4*q+1] + ev.z*wreg1[4*q+2] + ev.w*wreg1[4*q+3];
      }
      h0 = (h0 >= 0.0f) ? h0 : 0.01f*h0;
      h1 = (h1 >= 0.0f) ? h1 : 0.01f*h1;
      s_H[e*HPAD + lane] = h0;
      s_H[e*HPAD + 64 + lane] = h1;
    }
  }
  __syncthreads();

  for(int p = t; p < NSLOT*8; p += 256){
    int e = p >> 3, h = p & 7;
    const float4* Hp = (const float4*)(s_H + e*HPAD);
    const float4* Wp = (const float4*)(s_wa2t + h*HPAD);
    float acc = 0.f;
#pragma unroll
    for(int q=0; q<32; q++){
      float4 a = Hp[q], w = Wp[q];
      acc += a.x*w.x + a.y*w.y + a.z*w.z + a.w*w.w;
    }
    s_att[p] = s_val[e] ? acc : -1e30f;
  }
  __syncthreads();

  if(t < 64){
    int h = t & 7, g = t >> 3;
    float m = -INFINITY;
    for(int e=g; e<NSLOT; e+=8) m = fmaxf(m, s_att[e*8+h]);
    for(int off=8; off<64; off<<=1) m = fmaxf(m, __shfl_xor(m, off, 64));
    m = (m > -5e29f) ? m : 0.0f;
    float z = 0.0f;
    for(int e=g; e<NSLOT; e+=8){
      float p = expf(s_att[e*8+h] - m);
      s_att[e*8+h] = p; z += p;
    }
    for(int off=8; off<64; off<<=1) z += __shfl_xor(z, off, 64);
    float den = z + 1e-9f;
    for(int e=g; e<NSLOT; e+=8) s_att[e*8+h] = s_att[e*8+h] / den;
  }
  __syncthreads();

  {
    float a0=0.f,a1=0.f,a2=0.f,a3=0.f; int h = t >> 5;
    for(int e=0;e<NSLOT;e++){
      float w = s_att[e*8 + h];
      const float* Pr = P + s_src[e]*1024 + t;
      a0 += w*Pr[0]; a1 += w*Pr[256]; a2 += w*Pr[512]; a3 += w*Pr[768];
    }
    s_agg[0][t]=a0; s_agg[1][t]=a1; s_agg[2][t]=a2; s_agg[3][t]=a3;
  }
  __syncthreads();

  {  // Y = agg @ Wo ; thread handles dims k for c=cp,cp+1 -> Wo loaded once per 2 outputs
    int k = t & 127, cp = (t >> 7) * 2;
    float x0=0.f, x1=0.f;
    for(int u=0; u<256; u+=4){
      float w0=Wo[(u+0)*128+k], w1=Wo[(u+1)*128+k], w2=Wo[(u+2)*128+k], w3=Wo[(u+3)*128+k];
      float4 g0 = *(const float4*)&s_agg[cp][u];
      float4 g1 = *(const float4*)&s_agg[cp+1][u];
      x0 += g0.x*w0 + g0.y*w1 + g0.z*w2 + g0.w*w3;
      x1 += g1.x*w0 + g1.y*w1 + g1.z*w2 + g1.w*w3;
    }
    Y[d*512 + cp*128 + k]     = x0;
    Y[d*512 + (cp+1)*128 + k] = x1;
  }
}

// ---------------- K5: per-node MLP chain, 4 nodes/block ------------
__global__ __launch_bounds__(256) void k_node(
    const float* __restrict__ rots, const float* __restrict__ trans,
    const float* __restrict__ Y,
    const float* __restrict__ Wg, const float* __restrict__ Wf1,
    const float* __restrict__ Wf2, const float* __restrict__ Wr1,
    const float* __restrict__ br1, const float* __restrict__ Wr2,
    const float* __restrict__ br2, const float* __restrict__ Wr3,
    const float* __restrict__ br3, const float* __restrict__ Wt,
    const int* __restrict__ nmask, float* __restrict__ out)
{
  __shared__ __align__(16) float s_y[4][4][128];
  __shared__ __align__(16) float s_t1[4][128];
  __shared__ __align__(16) float s_bb0[4][128];
  __shared__ __align__(16) float s_gv[4][3][128];
  __shared__ __align__(16) float s_h1[4][256];
  __shared__ __align__(16) float s_h2[4][128];
  __shared__ float s_sc[4][8];

  int b = blockIdx.x, t = threadIdx.x;
  int half = t >> 7, k = t & 127;
  int nb = half*2;
  int dbase = b*4;
  for(int i=t; i<4*512; i+=256){
    int nd = i>>9, c=(i>>7)&3, kk=i&127;
    s_y[nd][c][kk] = Y[(dbase+nd)*512 + c*128 + kk];
  }
  __syncthreads();

  // stage A: gate, t1
  float g[2]={0.f,0.f}, f1[2]={0.f,0.f};
  for(int j=0;j<128;j+=4){
    float wg0=Wg[(j+0)*128+k], wg1=Wg[(j+1)*128+k], wg2=Wg[(j+2)*128+k], wg3=Wg[(j+3)*128+k];
    float wf0=Wf1[(j+0)*128+k], wf1_=Wf1[(j+1)*128+k], wf2_=Wf1[(j+2)*128+k], wf3=Wf1[(j+3)*128+k];
#pragma unroll
    for(int nn=0;nn<2;nn++){
      float4 yv = *(const float4*)&s_y[nb+nn][0][j];
      g[nn]  += yv.x*wg0 + yv.y*wg1 + yv.z*wg2 + yv.w*wg3;
      f1[nn] += yv.x*wf0 + yv.y*wf1_ + yv.z*wf2_ + yv.w*wf3;
    }
  }
  float gate[2];
#pragma unroll
  for(int nn=0;nn<2;nn++){
    gate[nn] = 1.0f/(1.0f + expf(-g[nn]));
    s_t1[nb+nn][k] = fmaxf(f1[nn], 0.0f);
  }
  __syncthreads();

  // stage B: f0, bb0, gated v
  float f0[2]={0.f,0.f};
  for(int j=0;j<128;j+=4){
    float w0=Wf2[(j+0)*128+k], w1=Wf2[(j+1)*128+k], w2=Wf2[(j+2)*128+k], w3=Wf2[(j+3)*128+k];
#pragma unroll
    for(int nn=0;nn<2;nn++){
      float4 tv = *(const float4*)&s_t1[nb+nn][j];
      f0[nn] += tv.x*w0 + tv.y*w1 + tv.z*w2 + tv.w*w3;
    }
  }
#pragma unroll
  for(int nn=0;nn<2;nn++){
    int d = dbase + nb + nn;
    float bb0 = s_y[nb+nn][0][k] + f0[nn];
    s_bb0[nb+nn][k] = bb0;
    out[OUT_BB + d*512 + k] = bb0;
#pragma unroll
    for(int c=1;c<4;c++){
      float v = s_y[nb+nn][c][k] * gate[nn];
      s_gv[nb+nn][c-1][k] = v;
      out[OUT_BB + d*512 + c*128 + k] = v;
    }
  }
  __syncthreads();

  // stage C: h1 (dims k, 128+k)
  float a1[2], a2[2];
  a1[0]=a1[1]=br1[k]; a2[0]=a2[1]=br1[128+k];
  for(int j=0;j<128;j+=4){
    float w10=Wr1[(j+0)*256+k],     w11=Wr1[(j+1)*256+k],     w12=Wr1[(j+2)*256+k],     w13=Wr1[(j+3)*256+k];
    float w20=Wr1[(j+0)*256+128+k], w21=Wr1[(j+1)*256+128+k], w22=Wr1[(j+2)*256+128+k], w23=Wr1[(j+3)*256+128+k];
#pragma unroll
    for(int nn=0;nn<2;nn++){
      float4 bv = *(const float4*)&s_bb0[nb+nn][j];
      a1[nn] += bv.x*w10 + bv.y*w11 + bv.z*w12 + bv.w*w13;
      a2[nn] += bv.x*w20 + bv.y*w21 + bv.z*w22 + bv.w*w23;
    }
  }
#pragma unroll
  for(int nn=0;nn<2;nn++){
    s_h1[nb+nn][k] = fmaxf(a1[nn], 0.0f);
    s_h1[nb+nn][128+k] = fmaxf(a2[nn], 0.0f);
  }
  __syncthreads();

  // stage D: h2
  float a[2]; a[0]=a[1]=br2[k];
  for(int j=0;j<256;j+=4){
    float w0=Wr2[(j+0)*128+k], w1=Wr2[(j+1)*128+k], w2=Wr2[(j+2)*128+k], w3=Wr2[(j+3)*128+k];
#pragma unroll
    for(int nn=0;nn<2;nn++){
      float4 hv = *(const float4*)&s_h1[nb+nn][j];
      a[nn] += hv.x*w0 + hv.y*w1 + hv.z*w2 + hv.w*w3;
    }
  }
#pragma unroll
  for(int nn=0;nn<2;nn++) s_h2[nb+nn][k] = fmaxf(a[nn], 0.0f);
  __syncthreads();

  // stage E: qv (12 threads) + tu (12 threads)
  if(t < 12){
    int nd = t/3, r = t%3;
    float q = br3[r];
    for(int kk=0;kk<128;kk++) q += s_h2[nd][kk] * Wr3[kk*6 + r];
    s_sc[nd][r] = q;
  } else if(t >= 32 && t < 44){
    int q2 = t-32; int nd = q2/3, i = q2%3;
    float s = 0.f;
    for(int kk=0;kk<128;kk++) s += s_gv[nd][i][kk] * Wt[kk];
    s_sc[nd][4+i] = s;
  }
  __syncthreads();

  if(t < 4){
    int d = dbase + t;
    int nz = nmask[d];
    float q1=s_sc[t][0], q2=s_sc[t][1], q3=s_sc[t][2];
    float nrm = sqrtf(1.0f + q1*q1 + q2*q2 + q3*q3);
    float w=1.0f/nrm, x=q1/nrm, y=q2/nrm, z=q3/nrm;
    float Ru[3][3];
    Ru[0][0]=1.f-2.f*(y*y+z*z); Ru[0][1]=2.f*(x*y-w*z);     Ru[0][2]=2.f*(x*z+w*y);
    Ru[1][0]=2.f*(x*y+w*z);     Ru[1][1]=1.f-2.f*(x*x+z*z); Ru[1][2]=2.f*(y*z-w*x);
    Ru[2][0]=2.f*(x*z-w*y);     Ru[2][1]=2.f*(y*z+w*x);     Ru[2][2]=1.f-2.f*(x*x+y*y);
    for(int i=0;i<3;i++){
      for(int j=0;j<3;j++){
        float rv;
        if(nz){
          rv = rots[d*9+i*3+0]*Ru[0][j] + rots[d*9+i*3+1]*Ru[1][j] + rots[d*9+i*3+2]*Ru[2][j];
        } else {
          rv = rots[d*9+i*3+j];
        }
        out[OUT_ROT + d*9 + i*3 + j] = rv;
      }
      float tv = trans[d*3+i];
      out[OUT_TRANS + d*3 + i] = nz ? (tv + s_sc[t][4+i]) : tv;
    }
  }
}

extern "C" void kernel_launch(void* const* d_in, const int* in_sizes, int n_in,
                              void* d_out, int out_size, void* d_ws, size_t ws_size,
                              hipStream_t stream)
{
  (void)in_sizes; (void)n_in; (void)out_size; (void)ws_size;
  const float* rots = (const float*)d_in[0];
  const float* trans = (const float*)d_in[1];
  const float* nf   = (const float*)d_in[2];
  const float* Wa1  = (const float*)d_in[3];
  const float* ba1  = (const float*)d_in[4];
  const float* Wa2  = (const float*)d_in[5];
  const float* Wv   = (const float*)d_in[6];
  const float* Wo   = (const float*)d_in[7];
  const float* Wg   = (const float*)d_in[8];
  const float* Wf1  = (const float*)d_in[9];
  const float* Wf2  = (const float*)d_in[10];
  const float* Wr1  = (const float*)d_in[11];
  const float* br1  = (const float*)d_in[12];
  const float* Wr2  = (const float*)d_in[13];
  const float* br2  = (const float*)d_in[14];
  const float* Wr3  = (const float*)d_in[15];
  const float* br3  = (const float*)d_in[16];
  const float* Wt   = (const float*)d_in[17];
  const int* xmask  = (const int*)d_in[19];
  const int* nmask  = (const int*)d_in[20];

  float* P = (float*)d_ws;                 // NN*1024 f32  (8 MB)
  float* U = P + NN*1024;                  // NN*128       (1 MB)
  float* V = U + NN*128;                   // NN*128       (1 MB)
  int* srcs = (int*)(V + NN*128);          // NN*40 int    (320 KB)
  float* Y  = (float*)(srcs + NN*NFIX);    // NN*512 f32   (4 MB)

  k_prep<<<NN/4, 256, 0, stream>>>(rots, trans, nf, Wa1, Wv, xmask, nmask, P, U, V);
  k_topk2<<<NN, 128, 0, stream>>>(trans, srcs);
  k_attn<<<NN, 256, 0, stream>>>(trans, Wa1, ba1, Wa2, Wo, U, V, P, srcs, Y);
  k_node<<<NN/4, 256, 0, stream>>>(rots, trans, Y, Wg, Wf1, Wf2,
                                   Wr1, br1, Wr2, br2, Wr3, br3, Wt,
                                   nmask, (float*)d_out);
}